// Round 12
// baseline (195.060 us; speedup 1.0000x reference)
//
#include <hip/hip_runtime.h>
#include <math.h>

#define HW 16384

typedef unsigned short u16;
typedef __attribute__((ext_vector_type(8))) short short8;
typedef __attribute__((ext_vector_type(16))) float f32x16;

union U16B {
  uint4 u;
  short8 v;
  u16 s[8];
};

__device__ inline u16 f2b(float f) {
  unsigned u = __float_as_uint(f);
  u += 0x7FFF + ((u >> 16) & 1);
  return (u16)(u >> 16);
}
__device__ inline float b2f(u16 h) {
  return __uint_as_float(((unsigned)h) << 16);
}

// ---------------------------------------------------------------------------
// Weight packing helpers (bf16 per-lane MFMA A-fragments).
// ---------------------------------------------------------------------------
__device__ inline u16 pack_frag(const float* __restrict__ w, int Cin, int O,
                                int OT, int d) {
  int j = d & 7;
  int lane = (d >> 3) & 63;
  int rest = d >> 9;
  int ot = rest % OT; rest /= OT;
  int ks = rest & 3; rest >>= 2;
  int kx = rest % 3; rest /= 3;
  int ky = rest % 3; int s = rest / 3;
  int och = ot * 32 + (lane & 31);
  int ch = s * 64 + ks * 16 + ((lane >> 5) << 3) + j;
  if (och >= O) return 0;
  return f2b(w[((size_t)och * Cin + ch) * 9 + ky * 3 + kx]);
}

__device__ inline u16 pack_def(const float* __restrict__ w, int d) {
  int j = d & 7;
  int lane = (d >> 3) & 63;
  int g = d >> 9;
  int ot = g & 1;
  int t = g >> 1;
  int ks = t & 3;
  int k = t >> 2;
  int och = ot * 32 + (lane & 31);
  int c = ks * 16 + ((lane >> 5) << 3) + j;
  return f2b(w[((size_t)och * 64 + c) * 9 + k]);
}

__device__ inline u16 pack_up(const float* __restrict__ w, int d) {
  int j = d & 7;
  int lane = (d >> 3) & 63;
  int g = d >> 9;
  int ot = g & 1;
  int rest = g >> 1;
  int ks = rest & 7;
  int t = rest >> 3;
  int och = ot * 32 + (lane & 31);
  int ci = ks * 16 + ((lane >> 5) << 3) + j;
  return f2b(w[((size_t)och * 128 + ci) * 4 + t]);
}

// ---------------------------------------------------------------------------
// setup_kernel = prep (weight packing) + cvt_nhwc (xl,xr) + cvt_xd, one launch.
// (unchanged — validated)
// ---------------------------------------------------------------------------
__global__ __launch_bounds__(256) void setup_kernel(
    const float* __restrict__ dl_w, const float* __restrict__ dr_w,
    const float* __restrict__ up_w, const float* __restrict__ cv_w,
    const float* __restrict__ offl_w, const float* __restrict__ offr_w,
    const float* __restrict__ r1a, const float* __restrict__ r1b,
    const float* __restrict__ r2a, const float* __restrict__ r2b,
    u16* __restrict__ wup, u16* __restrict__ wdl, u16* __restrict__ wdr,
    u16* __restrict__ wcv, u16* __restrict__ wofl, u16* __restrict__ wofr,
    u16* __restrict__ wr1a, u16* __restrict__ wr1b,
    u16* __restrict__ wr2a, u16* __restrict__ wr2b,
    const float* __restrict__ xl, const float* __restrict__ xr,
    u16* __restrict__ xlh, u16* __restrict__ xrh,
    const float* __restrict__ xd, u16* __restrict__ xdh) {
  __shared__ float sT[8448];
  int tid = threadIdx.x;
  int b = blockIdx.x;
  if (b < 1856) {
    int d = b * 256 + tid;
    if (d < 32768) { wup[d] = pack_up(up_w, d); return; }
    d -= 32768;
    if (d < 36864) { wdl[d] = pack_def(dl_w, d); return; }
    d -= 36864;
    if (d < 36864) { wdr[d] = pack_def(dr_w, d); return; }
    d -= 36864;
    if (d < 110592) { wcv[d] = pack_frag(cv_w, 192, 64, 2, d); return; }
    d -= 110592;
    if (d < 55296) { wofl[d] = pack_frag(offl_w, 192, 27, 1, d); return; }
    d -= 55296;
    if (d < 55296) { wofr[d] = pack_frag(offr_w, 192, 27, 1, d); return; }
    d -= 55296;
    if (d < 36864) { wr1a[d] = pack_frag(r1a, 64, 64, 2, d); return; }
    d -= 36864;
    if (d < 36864) { wr1b[d] = pack_frag(r1b, 64, 64, 2, d); return; }
    d -= 36864;
    if (d < 36864) { wr2a[d] = pack_frag(r2a, 64, 64, 2, d); return; }
    d -= 36864;
    if (d < 36864) { wr2b[d] = pack_frag(r2b, 64, 64, 2, d); return; }
    return;
  }
  b -= 1856;
  if (b < 512) {
    int y = b & 127;
    int pid = b >> 7;
    const float* src = (pid >> 1) ? xr : xl;
    u16* dst = (pid >> 1) ? xrh : xlh;
    int n = pid & 1;
#pragma unroll
    for (int i = 0; i < 8; ++i) {
      int q = tid + i * 256;
      int ch = q >> 5, pxq = q & 31;
      float4 v = *(const float4*)(src + ((size_t)(n * 64 + ch)) * HW + y * 128 + pxq * 4);
      *(float4*)&sT[ch * 132 + pxq * 4] = v;
    }
    __syncthreads();
    int px = tid >> 1, half = tid & 1;
    u16* op = dst + (((size_t)(n * 128 + y)) * 128 + px) * 64 + half * 32;
#pragma unroll
    for (int c = 0; c < 4; ++c) {
      uint4 v;
      int ob = (half * 32 + c * 8);
      v.x = (unsigned)f2b(sT[(ob + 0) * 132 + px]) | ((unsigned)f2b(sT[(ob + 1) * 132 + px]) << 16);
      v.y = (unsigned)f2b(sT[(ob + 2) * 132 + px]) | ((unsigned)f2b(sT[(ob + 3) * 132 + px]) << 16);
      v.z = (unsigned)f2b(sT[(ob + 4) * 132 + px]) | ((unsigned)f2b(sT[(ob + 5) * 132 + px]) << 16);
      v.w = (unsigned)f2b(sT[(ob + 6) * 132 + px]) | ((unsigned)f2b(sT[(ob + 7) * 132 + px]) << 16);
      *(uint4*)(op + c * 8) = v;
    }
    return;
  }
  b -= 512;
  {
    int r = b & 63;
    int n = b >> 6;
#pragma unroll
    for (int i = 0; i < 8; ++i) {
      int q = tid + i * 256;
      int ch = q >> 4, col4 = q & 15;
      float4 v = *(const float4*)(xd + ((size_t)(n * 128 + ch) * 64 + r) * 64 + col4 * 4);
      *(float4*)&sT[ch * 66 + col4 * 4] = v;
    }
    __syncthreads();
#pragma unroll
    for (int i = 0; i < 4; ++i) {
      int q = tid + i * 256;
      int col = q >> 4, cho = q & 15;
      uint4 v;
      int cb = cho * 8;
      v.x = (unsigned)f2b(sT[(cb + 0) * 66 + col]) | ((unsigned)f2b(sT[(cb + 1) * 66 + col]) << 16);
      v.y = (unsigned)f2b(sT[(cb + 2) * 66 + col]) | ((unsigned)f2b(sT[(cb + 3) * 66 + col]) << 16);
      v.z = (unsigned)f2b(sT[(cb + 4) * 66 + col]) | ((unsigned)f2b(sT[(cb + 5) * 66 + col]) << 16);
      v.w = (unsigned)f2b(sT[(cb + 6) * 66 + col]) | ((unsigned)f2b(sT[(cb + 7) * 66 + col]) << 16);
      *(uint4*)(xdh + (((size_t)(n * 64 + r)) * 64 + col) * 128 + cb) = v;
    }
  }
}

// ---------------------------------------------------------------------------
// Upsample + 2x2 conv, 1024 threads = 16 waves = 4 px-tiles x 4 taps.
// Same tiles/instruction count as R7 shape, 2x waves/SIMD. Two-round LDS
// reduce (acc0 then acc1) to fit 48KB buffer.
// ---------------------------------------------------------------------------
__global__ __launch_bounds__(1024) void upconv_mf(
    const u16* __restrict__ xdh, const u16* __restrict__ wup,
    const float* __restrict__ bias, u16* __restrict__ outH) {
  __shared__ float s_red[4][3][16][64];
  const int tid = threadIdx.x;
  const int lane = tid & 63;
  const int w = tid >> 6;
  const int p2 = w >> 2;
  const int t = w & 3;
  const int y = blockIdx.x;
  const int n = blockIdx.y;
  const int px = (p2 << 5) + (lane & 31);
  const int h = lane >> 5;

  f32x16 acc0, acc1;
#pragma unroll
  for (int i = 0; i < 16; ++i) { acc0[i] = 0.f; acc1[i] = 0.f; }

  const u16* xb = xdh + ((size_t)n * 64 * 64) * 128;
  const int ty = t >> 1, tx = t & 1;
  const int row = min((y + ty) >> 1, 63);
  const int col = min((px + tx) >> 1, 63);
  const u16* src = xb + ((size_t)(row * 64 + col)) * 128;
#pragma unroll
  for (int ks = 0; ks < 8; ++ks) {
    U16B bf;
    bf.u = *(const uint4*)(src + ks * 16 + h * 8);
    const u16* wp = wup + ((size_t)((t * 8 + ks) * 2)) * 512 + lane * 8;
    U16B a0, a1;
    a0.u = *(const uint4*)wp;
    a1.u = *(const uint4*)(wp + 512);
    acc0 = __builtin_amdgcn_mfma_f32_32x32x16_bf16(a0.v, bf.v, acc0, 0, 0, 0);
    acc1 = __builtin_amdgcn_mfma_f32_32x32x16_bf16(a1.v, bf.v, acc1, 0, 0, 0);
  }

  const bool zero = (y == 127) || (px == 127);
  const size_t pixb = (((size_t)(n * 128 + y)) * 128 + px) * 64;

  // round 1: ot = 0
  if (t != 0) {
#pragma unroll
    for (int i = 0; i < 16; ++i) s_red[p2][t - 1][i][lane] = acc0[i];
  }
  __syncthreads();
  if (t == 0) {
#pragma unroll
    for (int q = 0; q < 4; ++q) {
      int oo = 8 * q + 4 * h;
      float v[4];
#pragma unroll
      for (int r = 0; r < 4; ++r) {
        int i = q * 4 + r;
        float s = acc0[i] + s_red[p2][0][i][lane] + s_red[p2][1][i][lane] +
                  s_red[p2][2][i][lane];
        v[r] = zero ? 0.f : (s + bias[oo + r]);
      }
      ushort4 hh;
      hh.x = f2b(v[0]); hh.y = f2b(v[1]); hh.z = f2b(v[2]); hh.w = f2b(v[3]);
      *(ushort4*)(outH + pixb + oo) = hh;
    }
  }
  __syncthreads();
  // round 2: ot = 1
  if (t != 0) {
#pragma unroll
    for (int i = 0; i < 16; ++i) s_red[p2][t - 1][i][lane] = acc1[i];
  }
  __syncthreads();
  if (t == 0) {
#pragma unroll
    for (int q = 0; q < 4; ++q) {
      int oo = 32 + 8 * q + 4 * h;
      float v[4];
#pragma unroll
      for (int r = 0; r < 4; ++r) {
        int i = q * 4 + r;
        float s = acc1[i] + s_red[p2][0][i][lane] + s_red[p2][1][i][lane] +
                  s_red[p2][2][i][lane];
        v[r] = zero ? 0.f : (s + bias[oo + r]);
      }
      ushort4 hh;
      hh.x = f2b(v[0]); hh.y = f2b(v[1]); hh.z = f2b(v[2]); hh.w = f2b(v[3]);
      *(ushort4*)(outH + pixb + oo) = hh;
    }
  }
}

// ---------------------------------------------------------------------------
// MFMA 3x3 conv, pad=1, direct-global-load with per-segment ILP batching.
// (unchanged from R10 — validated)
// ---------------------------------------------------------------------------
template <int NSEG>
__global__ __launch_bounds__(512, 2) void mfconv_d(
    const u16* __restrict__ in0, const u16* __restrict__ in1,
    const u16* __restrict__ in2, const u16* __restrict__ wpk,
    const float* __restrict__ bias, const u16* __restrict__ resh,
    float* __restrict__ outF, u16* __restrict__ outH,
    int OT, int O, int mode) {
  __shared__ float s_red[2][3][16][64];
  const int tid = threadIdx.x;
  const int lane = tid & 63;
  const int w = tid >> 6;
  const int p2 = w >> 2;
  const int kq = w & 3;
  const int y = blockIdx.x >> 1;
  const int xh0 = (blockIdx.x & 1) << 6;
  const int ot = blockIdx.y;
  const int n = blockIdx.z;
  const int px = xh0 + (p2 << 5) + (lane & 31);
  const int h = lane >> 5;

  f32x16 acc;
#pragma unroll
  for (int i = 0; i < 16; ++i) acc[i] = 0.f;

#pragma unroll
  for (int s = 0; s < NSEG; ++s) {
    const u16* sp = (s == 0) ? in0 : ((s == 1) ? in1 : in2);
    const u16* bn = sp + ((size_t)n * 128) * 128 * 64;
    U16B bb[9], aa[9];
    bool vz[9];
#pragma unroll
    for (int t = 0; t < 9; ++t) {
      const int ky = t / 3, kx = t % 3;
      int r = y + ky - 1;
      int col = px + kx - 1;
      vz[t] = ((unsigned)r < 128u) && ((unsigned)col < 128u);
      int rc = min(max(r, 0), 127);
      int cc = min(max(col, 0), 127);
      bb[t].u = *(const uint4*)(bn + (size_t)rc * (128 * 64) + (size_t)cc * 64 +
                                h * 8 + kq * 16);
      aa[t].u = *(const uint4*)(wpk +
            ((size_t)((((s * 3 + ky) * 3 + kx) * 4 + kq) * OT + ot)) * 512 +
            lane * 8);
    }
#pragma unroll
    for (int t = 0; t < 9; ++t) {
      U16B bf = bb[t];
      if (!vz[t]) bf.u = make_uint4(0, 0, 0, 0);
      acc = __builtin_amdgcn_mfma_f32_32x32x16_bf16(aa[t].v, bf.v, acc, 0, 0, 0);
    }
  }

  if (kq != 0) {
#pragma unroll
    for (int i = 0; i < 16; ++i) s_red[p2][kq - 1][i][lane] = acc[i];
  }
  __syncthreads();
  if (kq == 0) {
#pragma unroll
    for (int i = 0; i < 16; ++i)
      acc[i] += s_red[p2][0][i][lane] + s_red[p2][1][i][lane] + s_red[p2][2][i][lane];
    const size_t pixb = ((size_t)(n * 128 + y)) * 128 + px;
    if (outH) {
#pragma unroll
      for (int q = 0; q < 4; ++q) {
        int oo = ot * 32 + 8 * q + 4 * h;
        float v[4];
#pragma unroll
        for (int r = 0; r < 4; ++r) v[r] = acc[q * 4 + r] + bias[oo + r];
        if (mode == 1) {
#pragma unroll
          for (int r = 0; r < 4; ++r) v[r] = fmaxf(v[r], 0.f);
        } else if (mode == 3) {
          ushort4 rv = *(const ushort4*)(resh + pixb * 64 + oo);
          v[0] += b2f(rv.x); v[1] += b2f(rv.y); v[2] += b2f(rv.z); v[3] += b2f(rv.w);
        }
        ushort4 hh;
        hh.x = f2b(v[0]); hh.y = f2b(v[1]); hh.z = f2b(v[2]); hh.w = f2b(v[3]);
        *(ushort4*)(outH + pixb * 64 + oo) = hh;
      }
    } else {
#pragma unroll
      for (int q = 0; q < 4; ++q) {
        int oo = ot * 32 + 8 * q + 4 * h;
#pragma unroll
        for (int r = 0; r < 4; ++r) {
          int och = oo + r;
          if (och >= O) continue;
          float v = acc[q * 4 + r] + bias[och];
          if (mode == 3) v += b2f(resh[pixb * 64 + och]);
          outF[((size_t)(n * O + och)) * HW + y * 128 + px] = v;
        }
      }
    }
  }
}

// ---------------------------------------------------------------------------
// Fused offset-conv + modulated deformable conv, 1024 threads = 16 waves =
// 4 px-tiles x 4 work-quarters. Phase 1: kq = ks-quarter (27 MFMA/wave).
// Phase 2: kq = tap group {0-2},{3-4},{5-6},{7-8} (same gather count as R7,
// spread over 2x waves). 4-way LDS reductions; phase-2 in two rounds
// (acc0 then acc1) reusing one 48KB buffer. Total LDS 61.5KB.
// ---------------------------------------------------------------------------
__global__ __launch_bounds__(1024) void deform_fused(
    const u16* __restrict__ in0, const u16* __restrict__ in1,
    const u16* __restrict__ in2, const u16* __restrict__ woff,
    const float* __restrict__ boff, const u16* __restrict__ xh,
    const u16* __restrict__ wdef, const float* __restrict__ bdef,
    u16* __restrict__ outH) {
  __shared__ float s_off[27][128];
  __shared__ float s_red[4][3][16][64];
  const int tid = threadIdx.x;
  const int lane = tid & 63;
  const int w = tid >> 6;
  const int p2 = w >> 2;
  const int kq = w & 3;
  const int y = blockIdx.x;
  const int n = blockIdx.y;
  const int px = (p2 << 5) + (lane & 31);
  const int h = lane >> 5;

  // ---- Phase 1: offset conv (wave = ks-quarter kq) ----
  {
    f32x16 acc;
#pragma unroll
    for (int i = 0; i < 16; ++i) acc[i] = 0.f;
#pragma unroll
    for (int s = 0; s < 3; ++s) {
      const u16* sp = (s == 0) ? in0 : ((s == 1) ? in1 : in2);
      const u16* bn = sp + ((size_t)n * 128) * 128 * 64;
#pragma unroll
      for (int ky = 0; ky < 3; ++ky) {
        int r = y + ky - 1;
        if ((unsigned)r >= 128u) continue;
        const u16* rp = bn + (size_t)r * (128 * 64);
        U16B bb[3], aa[3];
        bool vv[3];
#pragma unroll
        for (int kx = 0; kx < 3; ++kx) {
          int col = px + kx - 1;
          vv[kx] = (unsigned)col < 128u;
          int colc = min(max(col, 0), 127);
          bb[kx].u = *(const uint4*)(rp + (size_t)colc * 64 + h * 8 + kq * 16);
          aa[kx].u = *(const uint4*)(woff +
                ((size_t)(((s * 3 + ky) * 3 + kx) * 4 + kq)) * 512 + lane * 8);
        }
#pragma unroll
        for (int kx = 0; kx < 3; ++kx) {
          U16B bf = bb[kx];
          if (!vv[kx]) bf.u = make_uint4(0, 0, 0, 0);
          acc = __builtin_amdgcn_mfma_f32_32x32x16_bf16(aa[kx].v, bf.v, acc, 0, 0, 0);
        }
      }
    }
    if (kq != 0) {
#pragma unroll
      for (int i = 0; i < 16; ++i) s_red[p2][kq - 1][i][lane] = acc[i];
    }
    __syncthreads();
    if (kq == 0) {
#pragma unroll
      for (int q = 0; q < 4; ++q) {
#pragma unroll
        for (int r = 0; r < 4; ++r) {
          int och = 8 * q + 4 * h + r;
          if (och < 27) {
            int i = q * 4 + r;
            float v = acc[i] + s_red[p2][0][i][lane] + s_red[p2][1][i][lane] +
                      s_red[p2][2][i][lane] + boff[och];
            if (och >= 18) v = 1.f / (1.f + expf(-v));
            s_off[och][px] = v;
          }
        }
      }
    }
  }
  __syncthreads();

  // ---- Phase 2: deform gather + GEMM (wave = tap group kq) ----
  f32x16 acc0, acc1;
#pragma unroll
  for (int i = 0; i < 16; ++i) { acc0[i] = 0.f; acc1[i] = 0.f; }

  const u16* xb = xh + ((size_t)n * HW) * 64;
  const int kstart = kq ? (1 + 2 * kq) : 0;
  const int kcnt = kq ? 2 : 3;

#pragma unroll
  for (int kk = 0; kk < 3; ++kk) {
    if (kk >= kcnt) break;
    const int k = kstart + kk;
    const int ky = k / 3 - 1, kx = k % 3 - 1;
    float dy = s_off[2 * k][px];
    float dx = s_off[2 * k + 1][px];
    float m = s_off[18 + k][px];
    float py = dy + (float)(y + ky);
    float pxf = dx + (float)(px + kx);
    float fy = floorf(py), fxx = floorf(pxf);
    float wy = py - fy, wx = pxf - fxx;
    int iy0 = (int)fy, ix0 = (int)fxx;
    bool vy0 = (unsigned)iy0 < 128u, vy1 = (unsigned)(iy0 + 1) < 128u;
    bool vx0 = (unsigned)ix0 < 128u, vx1 = (unsigned)(ix0 + 1) < 128u;
    float omwy = 1.f - wy, omwx = 1.f - wx;
    float f00 = (vy0 && vx0) ? omwy * omwx * m : 0.f;
    float f01 = (vy0 && vx1) ? omwy * wx * m : 0.f;
    float f10 = (vy1 && vx0) ? wy * omwx * m : 0.f;
    float f11 = (vy1 && vx1) ? wy * wx * m : 0.f;
    int y0c = min(max(iy0, 0), 127), y1c = min(max(iy0 + 1, 0), 127);
    int x0c = min(max(ix0, 0), 127), x1c = min(max(ix0 + 1, 0), 127);
    const u16* r00 = xb + ((size_t)(y0c * 128 + x0c)) * 64 + h * 8;
    const u16* r01 = xb + ((size_t)(y0c * 128 + x1c)) * 64 + h * 8;
    const u16* r10 = xb + ((size_t)(y1c * 128 + x0c)) * 64 + h * 8;
    const u16* r11 = xb + ((size_t)(y1c * 128 + x1c)) * 64 + h * 8;

#pragma unroll
    for (int kp = 0; kp < 2; ++kp) {
      U16B g00[2], g01[2], g10[2], g11[2];
#pragma unroll
      for (int j2 = 0; j2 < 2; ++j2) {
        int ks = kp * 2 + j2;
        g00[j2].u = *(const uint4*)(r00 + ks * 16);
        g01[j2].u = *(const uint4*)(r01 + ks * 16);
        g10[j2].u = *(const uint4*)(r10 + ks * 16);
        g11[j2].u = *(const uint4*)(r11 + ks * 16);
      }
#pragma unroll
      for (int j2 = 0; j2 < 2; ++j2) {
        int ks = kp * 2 + j2;
        unsigned dw[4];
#pragma unroll
        for (int jj = 0; jj < 4; ++jj) {
          float s0 = f00 * b2f(g00[j2].s[2 * jj]) + f01 * b2f(g01[j2].s[2 * jj]) +
                     f10 * b2f(g10[j2].s[2 * jj]) + f11 * b2f(g11[j2].s[2 * jj]);
          float s1 = f00 * b2f(g00[j2].s[2 * jj + 1]) + f01 * b2f(g01[j2].s[2 * jj + 1]) +
                     f10 * b2f(g10[j2].s[2 * jj + 1]) + f11 * b2f(g11[j2].s[2 * jj + 1]);
          dw[jj] = (unsigned)f2b(s0) | ((unsigned)f2b(s1) << 16);
        }
        U16B bf;
        bf.u = make_uint4(dw[0], dw[1], dw[2], dw[3]);
        const u16* wp = wdef + ((size_t)((k * 4 + ks) * 2)) * 512 + lane * 8;
        U16B a0, a1;
        a0.u = *(const uint4*)wp;
        a1.u = *(const uint4*)(wp + 512);
        acc0 = __builtin_amdgcn_mfma_f32_32x32x16_bf16(a0.v, bf.v, acc0, 0, 0, 0);
        acc1 = __builtin_amdgcn_mfma_f32_32x32x16_bf16(a1.v, bf.v, acc1, 0, 0, 0);
      }
    }
  }

  const size_t pixb = (((size_t)(n * 128 + y)) * 128 + px) * 64;
  // round 1: ot = 0
  if (kq != 0) {
#pragma unroll
    for (int i = 0; i < 16; ++i) s_red[p2][kq - 1][i][lane] = acc0[i];
  }
  __syncthreads();
  if (kq == 0) {
#pragma unroll
    for (int q = 0; q < 4; ++q) {
      int oo = 8 * q + 4 * h;
      float v[4];
#pragma unroll
      for (int r = 0; r < 4; ++r) {
        int i = q * 4 + r;
        v[r] = acc0[i] + s_red[p2][0][i][lane] + s_red[p2][1][i][lane] +
               s_red[p2][2][i][lane] + bdef[oo + r];
      }
      ushort4 hh;
      hh.x = f2b(v[0]); hh.y = f2b(v[1]); hh.z = f2b(v[2]); hh.w = f2b(v[3]);
      *(ushort4*)(outH + pixb + oo) = hh;
    }
  }
  __syncthreads();
  // round 2: ot = 1
  if (kq != 0) {
#pragma unroll
    for (int i = 0; i < 16; ++i) s_red[p2][kq - 1][i][lane] = acc1[i];
  }
  __syncthreads();
  if (kq == 0) {
#pragma unroll
    for (int q = 0; q < 4; ++q) {
      int oo = 32 + 8 * q + 4 * h;
      float v[4];
#pragma unroll
      for (int r = 0; r < 4; ++r) {
        int i = q * 4 + r;
        v[r] = acc1[i] + s_red[p2][0][i][lane] + s_red[p2][1][i][lane] +
               s_red[p2][2][i][lane] + bdef[oo + r];
      }
      ushort4 hh;
      hh.x = f2b(v[0]); hh.y = f2b(v[1]); hh.z = f2b(v[2]); hh.w = f2b(v[3]);
      *(ushort4*)(outH + pixb + oo) = hh;
    }
  }
}

// ---------------------------------------------------------------------------
extern "C" void kernel_launch(void* const* d_in, const int* in_sizes, int n_in,
                              void* d_out, int out_size, void* d_ws, size_t ws_size,
                              hipStream_t stream) {
  const float* xd = (const float*)d_in[0];
  const float* xl = (const float*)d_in[1];
  const float* xr = (const float*)d_in[2];
  const float* up_w = (const float*)d_in[3];
  const float* up_b = (const float*)d_in[4];
  const float* offl_w = (const float*)d_in[5];
  const float* offl_b = (const float*)d_in[6];
  const float* dl_w = (const float*)d_in[7];
  const float* dl_b = (const float*)d_in[8];
  const float* offr_w = (const float*)d_in[9];
  const float* offr_b = (const float*)d_in[10];
  const float* dr_w = (const float*)d_in[11];
  const float* dr_b = (const float*)d_in[12];
  const float* cv_w = (const float*)d_in[13];
  const float* cv_b = (const float*)d_in[14];
  const float* rb1_w1 = (const float*)d_in[15];
  const float* rb1_w2 = (const float*)d_in[16];
  const float* rb2_w1 = (const float*)d_in[17];
  const float* rb2_w2 = (const float*)d_in[18];
  const float* rb1_b1 = (const float*)d_in[19];
  const float* rb1_b2 = (const float*)d_in[20];
  const float* rb2_b1 = (const float*)d_in[21];
  const float* rb2_b2 = (const float*)d_in[22];

  float* ws = (float*)d_ws;
  u16* hb = (u16*)(ws + 1769472);
  u16* xlh = hb;                   // 2097152 each
  u16* xrh = hb + 2097152;
  u16* xdph = hb + 4194304;
  u16* xl2h = hb + 6291456;
  u16* xr2h = hb + 8388608;
  u16* t0h = hb + 10485760;
  u16* t1h = hb + 12582912;
  u16* t2h = hb + 14680064;
  u16* t3h = hb + 16777216;
  u16* xdh = hb + 18874368;        // 1048576 (2*64*64*128)
  u16* wcv = hb + 19922944;        // 110592
  u16* wofl = hb + 20033536;       // 55296
  u16* wofr = hb + 20088832;       // 55296
  u16* wr1a = hb + 20144128;       // 36864
  u16* wr1b = hb + 20180992;
  u16* wr2a = hb + 20217856;
  u16* wr2b = hb + 20254720;
  u16* wdl = hb + 20291584;        // 36864
  u16* wdr = hb + 20328448;        // 36864
  u16* wup = hb + 20365312;        // 32768
  float* outp = (float*)d_out;

  hipLaunchKernelGGL(setup_kernel, dim3(2496), dim3(256), 0, stream,
                     dl_w, dr_w, up_w, cv_w, offl_w, offr_w, rb1_w1, rb1_w2,
                     rb2_w1, rb2_w2, wup, wdl, wdr, wcv, wofl, wofr, wr1a,
                     wr1b, wr2a, wr2b, xl, xr, xlh, xrh, xd, xdh);
  hipLaunchKernelGGL(upconv_mf, dim3(128, 2), dim3(1024), 0, stream,
                     xdh, wup, up_b, xdph);
  hipLaunchKernelGGL(deform_fused, dim3(128, 2), dim3(1024), 0, stream,
                     xlh, xrh, xdph, wofl, offl_b, xlh, wdl, dl_b, xl2h);
  hipLaunchKernelGGL(deform_fused, dim3(128, 2), dim3(1024), 0, stream,
                     xl2h, xrh, xdph, wofr, offr_b, xrh, wdr, dr_b, xr2h);
  hipLaunchKernelGGL(mfconv_d<3>, dim3(256, 2, 2), dim3(512), 0, stream,
                     xl2h, xr2h, xdph, wcv, cv_b, (const u16*)nullptr,
                     (float*)nullptr, t0h, 2, 64, 1);
  hipLaunchKernelGGL(mfconv_d<1>, dim3(256, 2, 2), dim3(512), 0, stream,
                     t0h, (const u16*)nullptr, (const u16*)nullptr, wr1a,
                     rb1_b1, (const u16*)nullptr, (float*)nullptr, t1h,
                     2, 64, 1);
  hipLaunchKernelGGL(mfconv_d<1>, dim3(256, 2, 2), dim3(512), 0, stream,
                     t1h, (const u16*)nullptr, (const u16*)nullptr, wr1b,
                     rb1_b2, t0h, (float*)nullptr, t2h, 2, 64, 3);
  hipLaunchKernelGGL(mfconv_d<1>, dim3(256, 2, 2), dim3(512), 0, stream,
                     t2h, (const u16*)nullptr, (const u16*)nullptr, wr2a,
                     rb2_b1, (const u16*)nullptr, (float*)nullptr, t3h,
                     2, 64, 1);
  hipLaunchKernelGGL(mfconv_d<1>, dim3(256, 2, 2), dim3(512), 0, stream,
                     t3h, (const u16*)nullptr, (const u16*)nullptr, wr2b,
                     rb2_b2, t2h, outp, (u16*)nullptr, 2, 64, 3);
}

// Round 13
// 173.270 us; speedup vs baseline: 1.1258x; 1.1258x over previous
//
#include <hip/hip_runtime.h>
#include <math.h>

#define HW 16384

typedef unsigned short u16;
typedef __attribute__((ext_vector_type(8))) short short8;
typedef __attribute__((ext_vector_type(16))) float f32x16;

union U16B {
  uint4 u;
  short8 v;
  u16 s[8];
};

__device__ inline u16 f2b(float f) {
  unsigned u = __float_as_uint(f);
  u += 0x7FFF + ((u >> 16) & 1);
  return (u16)(u >> 16);
}
__device__ inline float b2f(u16 h) {
  return __uint_as_float(((unsigned)h) << 16);
}

// ---------------------------------------------------------------------------
// Weight packing helpers (bf16 per-lane MFMA A-fragments).
// ---------------------------------------------------------------------------
__device__ inline u16 pack_frag(const float* __restrict__ w, int Cin, int O,
                                int OT, int d) {
  int j = d & 7;
  int lane = (d >> 3) & 63;
  int rest = d >> 9;
  int ot = rest % OT; rest /= OT;
  int ks = rest & 3; rest >>= 2;
  int kx = rest % 3; rest /= 3;
  int ky = rest % 3; int s = rest / 3;
  int och = ot * 32 + (lane & 31);
  int ch = s * 64 + ks * 16 + ((lane >> 5) << 3) + j;
  if (och >= O) return 0;
  return f2b(w[((size_t)och * Cin + ch) * 9 + ky * 3 + kx]);
}

__device__ inline u16 pack_def(const float* __restrict__ w, int d) {
  int j = d & 7;
  int lane = (d >> 3) & 63;
  int g = d >> 9;
  int ot = g & 1;
  int t = g >> 1;
  int ks = t & 3;
  int k = t >> 2;
  int och = ot * 32 + (lane & 31);
  int c = ks * 16 + ((lane >> 5) << 3) + j;
  return f2b(w[((size_t)och * 64 + c) * 9 + k]);
}

__device__ inline u16 pack_up(const float* __restrict__ w, int d) {
  int j = d & 7;
  int lane = (d >> 3) & 63;
  int g = d >> 9;
  int ot = g & 1;
  int rest = g >> 1;
  int ks = rest & 7;
  int t = rest >> 3;
  int och = ot * 32 + (lane & 31);
  int ci = ks * 16 + ((lane >> 5) << 3) + j;
  return f2b(w[((size_t)och * 128 + ci) * 4 + t]);
}

// ---------------------------------------------------------------------------
// setup_kernel (unchanged — validated)
// ---------------------------------------------------------------------------
__global__ __launch_bounds__(256) void setup_kernel(
    const float* __restrict__ dl_w, const float* __restrict__ dr_w,
    const float* __restrict__ up_w, const float* __restrict__ cv_w,
    const float* __restrict__ offl_w, const float* __restrict__ offr_w,
    const float* __restrict__ r1a, const float* __restrict__ r1b,
    const float* __restrict__ r2a, const float* __restrict__ r2b,
    u16* __restrict__ wup, u16* __restrict__ wdl, u16* __restrict__ wdr,
    u16* __restrict__ wcv, u16* __restrict__ wofl, u16* __restrict__ wofr,
    u16* __restrict__ wr1a, u16* __restrict__ wr1b,
    u16* __restrict__ wr2a, u16* __restrict__ wr2b,
    const float* __restrict__ xl, const float* __restrict__ xr,
    u16* __restrict__ xlh, u16* __restrict__ xrh,
    const float* __restrict__ xd, u16* __restrict__ xdh) {
  __shared__ float sT[8448];
  int tid = threadIdx.x;
  int b = blockIdx.x;
  if (b < 1856) {
    int d = b * 256 + tid;
    if (d < 32768) { wup[d] = pack_up(up_w, d); return; }
    d -= 32768;
    if (d < 36864) { wdl[d] = pack_def(dl_w, d); return; }
    d -= 36864;
    if (d < 36864) { wdr[d] = pack_def(dr_w, d); return; }
    d -= 36864;
    if (d < 110592) { wcv[d] = pack_frag(cv_w, 192, 64, 2, d); return; }
    d -= 110592;
    if (d < 55296) { wofl[d] = pack_frag(offl_w, 192, 27, 1, d); return; }
    d -= 55296;
    if (d < 55296) { wofr[d] = pack_frag(offr_w, 192, 27, 1, d); return; }
    d -= 55296;
    if (d < 36864) { wr1a[d] = pack_frag(r1a, 64, 64, 2, d); return; }
    d -= 36864;
    if (d < 36864) { wr1b[d] = pack_frag(r1b, 64, 64, 2, d); return; }
    d -= 36864;
    if (d < 36864) { wr2a[d] = pack_frag(r2a, 64, 64, 2, d); return; }
    d -= 36864;
    if (d < 36864) { wr2b[d] = pack_frag(r2b, 64, 64, 2, d); return; }
    return;
  }
  b -= 1856;
  if (b < 512) {
    int y = b & 127;
    int pid = b >> 7;
    const float* src = (pid >> 1) ? xr : xl;
    u16* dst = (pid >> 1) ? xrh : xlh;
    int n = pid & 1;
#pragma unroll
    for (int i = 0; i < 8; ++i) {
      int q = tid + i * 256;
      int ch = q >> 5, pxq = q & 31;
      float4 v = *(const float4*)(src + ((size_t)(n * 64 + ch)) * HW + y * 128 + pxq * 4);
      *(float4*)&sT[ch * 132 + pxq * 4] = v;
    }
    __syncthreads();
    int px = tid >> 1, half = tid & 1;
    u16* op = dst + (((size_t)(n * 128 + y)) * 128 + px) * 64 + half * 32;
#pragma unroll
    for (int c = 0; c < 4; ++c) {
      uint4 v;
      int ob = (half * 32 + c * 8);
      v.x = (unsigned)f2b(sT[(ob + 0) * 132 + px]) | ((unsigned)f2b(sT[(ob + 1) * 132 + px]) << 16);
      v.y = (unsigned)f2b(sT[(ob + 2) * 132 + px]) | ((unsigned)f2b(sT[(ob + 3) * 132 + px]) << 16);
      v.z = (unsigned)f2b(sT[(ob + 4) * 132 + px]) | ((unsigned)f2b(sT[(ob + 5) * 132 + px]) << 16);
      v.w = (unsigned)f2b(sT[(ob + 6) * 132 + px]) | ((unsigned)f2b(sT[(ob + 7) * 132 + px]) << 16);
      *(uint4*)(op + c * 8) = v;
    }
    return;
  }
  b -= 512;
  {
    int r = b & 63;
    int n = b >> 6;
#pragma unroll
    for (int i = 0; i < 8; ++i) {
      int q = tid + i * 256;
      int ch = q >> 4, col4 = q & 15;
      float4 v = *(const float4*)(xd + ((size_t)(n * 128 + ch) * 64 + r) * 64 + col4 * 4);
      *(float4*)&sT[ch * 66 + col4 * 4] = v;
    }
    __syncthreads();
#pragma unroll
    for (int i = 0; i < 4; ++i) {
      int q = tid + i * 256;
      int col = q >> 4, cho = q & 15;
      uint4 v;
      int cb = cho * 8;
      v.x = (unsigned)f2b(sT[(cb + 0) * 66 + col]) | ((unsigned)f2b(sT[(cb + 1) * 66 + col]) << 16);
      v.y = (unsigned)f2b(sT[(cb + 2) * 66 + col]) | ((unsigned)f2b(sT[(cb + 3) * 66 + col]) << 16);
      v.z = (unsigned)f2b(sT[(cb + 4) * 66 + col]) | ((unsigned)f2b(sT[(cb + 5) * 66 + col]) << 16);
      v.w = (unsigned)f2b(sT[(cb + 6) * 66 + col]) | ((unsigned)f2b(sT[(cb + 7) * 66 + col]) << 16);
      *(uint4*)(xdh + (((size_t)(n * 64 + r)) * 64 + col) * 128 + cb) = v;
    }
  }
}

// ---------------------------------------------------------------------------
// Upsample + 2x2 conv (unchanged from R11 — validated)
// ---------------------------------------------------------------------------
__global__ __launch_bounds__(1024) void upconv_mf(
    const u16* __restrict__ xdh, const u16* __restrict__ wup,
    const float* __restrict__ bias, u16* __restrict__ outH) {
  __shared__ float s_red[4][3][16][64];
  const int tid = threadIdx.x;
  const int lane = tid & 63;
  const int w = tid >> 6;
  const int p2 = w >> 2;
  const int t = w & 3;
  const int y = blockIdx.x;
  const int n = blockIdx.y;
  const int px = (p2 << 5) + (lane & 31);
  const int h = lane >> 5;

  f32x16 acc0, acc1;
#pragma unroll
  for (int i = 0; i < 16; ++i) { acc0[i] = 0.f; acc1[i] = 0.f; }

  const u16* xb = xdh + ((size_t)n * 64 * 64) * 128;
  const int ty = t >> 1, tx = t & 1;
  const int row = min((y + ty) >> 1, 63);
  const int col = min((px + tx) >> 1, 63);
  const u16* src = xb + ((size_t)(row * 64 + col)) * 128;
#pragma unroll
  for (int ks = 0; ks < 8; ++ks) {
    U16B bf;
    bf.u = *(const uint4*)(src + ks * 16 + h * 8);
    const u16* wp = wup + ((size_t)((t * 8 + ks) * 2)) * 512 + lane * 8;
    U16B a0, a1;
    a0.u = *(const uint4*)wp;
    a1.u = *(const uint4*)(wp + 512);
    acc0 = __builtin_amdgcn_mfma_f32_32x32x16_bf16(a0.v, bf.v, acc0, 0, 0, 0);
    acc1 = __builtin_amdgcn_mfma_f32_32x32x16_bf16(a1.v, bf.v, acc1, 0, 0, 0);
  }

  const bool zero = (y == 127) || (px == 127);
  const size_t pixb = (((size_t)(n * 128 + y)) * 128 + px) * 64;

  if (t != 0) {
#pragma unroll
    for (int i = 0; i < 16; ++i) s_red[p2][t - 1][i][lane] = acc0[i];
  }
  __syncthreads();
  if (t == 0) {
#pragma unroll
    for (int q = 0; q < 4; ++q) {
      int oo = 8 * q + 4 * h;
      float v[4];
#pragma unroll
      for (int r = 0; r < 4; ++r) {
        int i = q * 4 + r;
        float s = acc0[i] + s_red[p2][0][i][lane] + s_red[p2][1][i][lane] +
                  s_red[p2][2][i][lane];
        v[r] = zero ? 0.f : (s + bias[oo + r]);
      }
      ushort4 hh;
      hh.x = f2b(v[0]); hh.y = f2b(v[1]); hh.z = f2b(v[2]); hh.w = f2b(v[3]);
      *(ushort4*)(outH + pixb + oo) = hh;
    }
  }
  __syncthreads();
  if (t != 0) {
#pragma unroll
    for (int i = 0; i < 16; ++i) s_red[p2][t - 1][i][lane] = acc1[i];
  }
  __syncthreads();
  if (t == 0) {
#pragma unroll
    for (int q = 0; q < 4; ++q) {
      int oo = 32 + 8 * q + 4 * h;
      float v[4];
#pragma unroll
      for (int r = 0; r < 4; ++r) {
        int i = q * 4 + r;
        float s = acc1[i] + s_red[p2][0][i][lane] + s_red[p2][1][i][lane] +
                  s_red[p2][2][i][lane];
        v[r] = zero ? 0.f : (s + bias[oo + r]);
      }
      ushort4 hh;
      hh.x = f2b(v[0]); hh.y = f2b(v[1]); hh.z = f2b(v[2]); hh.w = f2b(v[3]);
      *(ushort4*)(outH + pixb + oo) = hh;
    }
  }
}

// ---------------------------------------------------------------------------
// MFMA 3x3 conv (unchanged from R10 — validated)
// ---------------------------------------------------------------------------
template <int NSEG>
__global__ __launch_bounds__(512, 2) void mfconv_d(
    const u16* __restrict__ in0, const u16* __restrict__ in1,
    const u16* __restrict__ in2, const u16* __restrict__ wpk,
    const float* __restrict__ bias, const u16* __restrict__ resh,
    float* __restrict__ outF, u16* __restrict__ outH,
    int OT, int O, int mode) {
  __shared__ float s_red[2][3][16][64];
  const int tid = threadIdx.x;
  const int lane = tid & 63;
  const int w = tid >> 6;
  const int p2 = w >> 2;
  const int kq = w & 3;
  const int y = blockIdx.x >> 1;
  const int xh0 = (blockIdx.x & 1) << 6;
  const int ot = blockIdx.y;
  const int n = blockIdx.z;
  const int px = xh0 + (p2 << 5) + (lane & 31);
  const int h = lane >> 5;

  f32x16 acc;
#pragma unroll
  for (int i = 0; i < 16; ++i) acc[i] = 0.f;

#pragma unroll
  for (int s = 0; s < NSEG; ++s) {
    const u16* sp = (s == 0) ? in0 : ((s == 1) ? in1 : in2);
    const u16* bn = sp + ((size_t)n * 128) * 128 * 64;
    U16B bb[9], aa[9];
    bool vz[9];
#pragma unroll
    for (int t = 0; t < 9; ++t) {
      const int ky = t / 3, kx = t % 3;
      int r = y + ky - 1;
      int col = px + kx - 1;
      vz[t] = ((unsigned)r < 128u) && ((unsigned)col < 128u);
      int rc = min(max(r, 0), 127);
      int cc = min(max(col, 0), 127);
      bb[t].u = *(const uint4*)(bn + (size_t)rc * (128 * 64) + (size_t)cc * 64 +
                                h * 8 + kq * 16);
      aa[t].u = *(const uint4*)(wpk +
            ((size_t)((((s * 3 + ky) * 3 + kx) * 4 + kq) * OT + ot)) * 512 +
            lane * 8);
    }
#pragma unroll
    for (int t = 0; t < 9; ++t) {
      U16B bf = bb[t];
      if (!vz[t]) bf.u = make_uint4(0, 0, 0, 0);
      acc = __builtin_amdgcn_mfma_f32_32x32x16_bf16(aa[t].v, bf.v, acc, 0, 0, 0);
    }
  }

  if (kq != 0) {
#pragma unroll
    for (int i = 0; i < 16; ++i) s_red[p2][kq - 1][i][lane] = acc[i];
  }
  __syncthreads();
  if (kq == 0) {
#pragma unroll
    for (int i = 0; i < 16; ++i)
      acc[i] += s_red[p2][0][i][lane] + s_red[p2][1][i][lane] + s_red[p2][2][i][lane];
    const size_t pixb = ((size_t)(n * 128 + y)) * 128 + px;
    if (outH) {
#pragma unroll
      for (int q = 0; q < 4; ++q) {
        int oo = ot * 32 + 8 * q + 4 * h;
        float v[4];
#pragma unroll
        for (int r = 0; r < 4; ++r) v[r] = acc[q * 4 + r] + bias[oo + r];
        if (mode == 1) {
#pragma unroll
          for (int r = 0; r < 4; ++r) v[r] = fmaxf(v[r], 0.f);
        } else if (mode == 3) {
          ushort4 rv = *(const ushort4*)(resh + pixb * 64 + oo);
          v[0] += b2f(rv.x); v[1] += b2f(rv.y); v[2] += b2f(rv.z); v[3] += b2f(rv.w);
        }
        ushort4 hh;
        hh.x = f2b(v[0]); hh.y = f2b(v[1]); hh.z = f2b(v[2]); hh.w = f2b(v[3]);
        *(ushort4*)(outH + pixb * 64 + oo) = hh;
      }
    } else {
#pragma unroll
      for (int q = 0; q < 4; ++q) {
        int oo = ot * 32 + 8 * q + 4 * h;
#pragma unroll
        for (int r = 0; r < 4; ++r) {
          int och = oo + r;
          if (och >= O) continue;
          float v = acc[q * 4 + r] + bias[och];
          if (mode == 3) v += b2f(resh[pixb * 64 + och]);
          outF[((size_t)(n * O + och)) * HW + y * 128 + px] = v;
        }
      }
    }
  }
}

// ---------------------------------------------------------------------------
// Fused offset-conv + deformable conv with FULL-LINE loads via LDS.
// 1024 thr = 16 waves; block = one row (128 px).
// LDS: s_off[27][128] (13.8KB) + 49.9KB union buffer (stg / sampled / s_red).
// Phase 1: per seg, stage 3 rows coalesced (lane = px*slice, 8 lines/instr)
//   into stg[ky][cg][130][8]; wave (p2,kq) runs 9 MFMA from ds_read frags.
// Phase 2: 3 chunks of 3 taps: gather-blend (lane = px*slice, full-line
//   corner loads) into stg[tt][cg][130][8]; wave (p2,kq) runs chunk MFMAs.
// Reductions: two rounds over union buffer as s_red.
// ---------------------------------------------------------------------------
__global__ __launch_bounds__(1024) void deform_fused(
    const u16* __restrict__ in0, const u16* __restrict__ in1,
    const u16* __restrict__ in2, const u16* __restrict__ woff,
    const float* __restrict__ boff, const u16* __restrict__ xh,
    const u16* __restrict__ wdef, const float* __restrict__ bdef,
    u16* __restrict__ outH) {
  __shared__ float s_off[27][128];
  __shared__ __align__(16) unsigned char s_un[49920];
  u16* stg = (u16*)s_un;            // [e<3][cg<8][130][8ch]
  float* s_redf = (float*)s_un;     // [p2<4][3][16][64]

  const int tid = threadIdx.x;
  const int lane = tid & 63;
  const int w = tid >> 6;
  const int p2 = w >> 2;
  const int kq = w & 3;
  const int y = blockIdx.x;
  const int n = blockIdx.y;
  const int px = (p2 << 5) + (lane & 31);
  const int h = lane >> 5;
  // gather-lane mapping: 8 px x 8 ch-slices
  const int gpx = lane >> 3;   // px within group of 8
  const int gcs = lane & 7;    // ch slice (8 ch)

  auto stg_at = [&](int e, int cg, int p) -> u16* {
    return stg + (((e * 8 + cg) * 130 + p) << 3);
  };

  // ================= Phase 1: offset conv =================
  f32x16 acc;
#pragma unroll
  for (int i = 0; i < 16; ++i) acc[i] = 0.f;

  for (int s = 0; s < 3; ++s) {
    const u16* sp = (s == 0) ? in0 : ((s == 1) ? in1 : in2);
    const u16* bn = sp + ((size_t)n * 128) * 128 * 64;
    // stage 3 rows: 48 units (ky, g), 3 per wave
    for (int i = w; i < 48; i += 16) {
      int ky = i >> 4, g = i & 15;
      int row = y + ky - 1;
      int ppx = g * 8 + gpx;
      uint4 v = make_uint4(0, 0, 0, 0);
      if ((unsigned)row < 128u)
        v = *(const uint4*)(bn + (size_t)row * (128 * 64) + (size_t)ppx * 64 + gcs * 8);
      *(uint4*)stg_at(ky, gcs, ppx) = v;
    }
    __syncthreads();
#pragma unroll
    for (int ky = 0; ky < 3; ++ky) {
#pragma unroll
      for (int kx = 0; kx < 3; ++kx) {
        int pxc = px + kx - 1;
        bool valid = (unsigned)pxc < 128u;
        int pxcc = min(max(pxc, 0), 127);
        U16B bf;
        bf.u = *(const uint4*)stg_at(ky, kq * 2 + h, pxcc);
        if (!valid) bf.u = make_uint4(0, 0, 0, 0);
        U16B a;
        a.u = *(const uint4*)(woff +
              ((size_t)(((s * 3 + ky) * 3 + kx) * 4 + kq)) * 512 + lane * 8);
        acc = __builtin_amdgcn_mfma_f32_32x32x16_bf16(a.v, bf.v, acc, 0, 0, 0);
      }
    }
    __syncthreads();  // before restage
  }

  // reduce phase-1 accs -> s_off
  if (kq != 0) {
#pragma unroll
    for (int i = 0; i < 16; ++i) s_redf[((p2 * 3 + (kq - 1)) * 16 + i) * 64 + lane] = acc[i];
  }
  __syncthreads();
  if (kq == 0) {
#pragma unroll
    for (int q = 0; q < 4; ++q) {
#pragma unroll
      for (int r = 0; r < 4; ++r) {
        int och = 8 * q + 4 * h + r;
        if (och < 27) {
          int i = q * 4 + r;
          float v = acc[i] + s_redf[((p2 * 3 + 0) * 16 + i) * 64 + lane] +
                    s_redf[((p2 * 3 + 1) * 16 + i) * 64 + lane] +
                    s_redf[((p2 * 3 + 2) * 16 + i) * 64 + lane] + boff[och];
          if (och >= 18) v = 1.f / (1.f + expf(-v));
          s_off[och][px] = v;
        }
      }
    }
  }
  __syncthreads();

  // ================= Phase 2: deform =================
  f32x16 acc0, acc1;
#pragma unroll
  for (int i = 0; i < 16; ++i) { acc0[i] = 0.f; acc1[i] = 0.f; }

  const u16* xb = xh + ((size_t)n * HW) * 64;

  for (int tc = 0; tc < 3; ++tc) {
    // gather-blend chunk: 48 units (tt, g), 3 per wave
    for (int i = w; i < 48; i += 16) {
      int tt = i >> 4, g = i & 15;
      int t = tc * 3 + tt;
      int ppx = g * 8 + gpx;
      int ky = t / 3 - 1, kx = t % 3 - 1;
      float dy = s_off[2 * t][ppx];
      float dx = s_off[2 * t + 1][ppx];
      float m = s_off[18 + t][ppx];
      float py = dy + (float)(y + ky);
      float pxf = dx + (float)(ppx + kx);
      float fy = floorf(py), fxx = floorf(pxf);
      float wy = py - fy, wx = pxf - fxx;
      int iy0 = (int)fy, ix0 = (int)fxx;
      bool vy0 = (unsigned)iy0 < 128u, vy1 = (unsigned)(iy0 + 1) < 128u;
      bool vx0 = (unsigned)ix0 < 128u, vx1 = (unsigned)(ix0 + 1) < 128u;
      float omwy = 1.f - wy, omwx = 1.f - wx;
      float f00 = (vy0 && vx0) ? omwy * omwx * m : 0.f;
      float f01 = (vy0 && vx1) ? omwy * wx * m : 0.f;
      float f10 = (vy1 && vx0) ? wy * omwx * m : 0.f;
      float f11 = (vy1 && vx1) ? wy * wx * m : 0.f;
      int y0c = min(max(iy0, 0), 127), y1c = min(max(iy0 + 1, 0), 127);
      int x0c = min(max(ix0, 0), 127), x1c = min(max(ix0 + 1, 0), 127);
      U16B v00, v01, v10, v11;
      v00.u = *(const uint4*)(xb + ((size_t)(y0c * 128 + x0c)) * 64 + gcs * 8);
      v01.u = *(const uint4*)(xb + ((size_t)(y0c * 128 + x1c)) * 64 + gcs * 8);
      v10.u = *(const uint4*)(xb + ((size_t)(y1c * 128 + x0c)) * 64 + gcs * 8);
      v11.u = *(const uint4*)(xb + ((size_t)(y1c * 128 + x1c)) * 64 + gcs * 8);
      unsigned dw[4];
#pragma unroll
      for (int jj = 0; jj < 4; ++jj) {
        float s0 = f00 * b2f(v00.s[2 * jj]) + f01 * b2f(v01.s[2 * jj]) +
                   f10 * b2f(v10.s[2 * jj]) + f11 * b2f(v11.s[2 * jj]);
        float s1 = f00 * b2f(v00.s[2 * jj + 1]) + f01 * b2f(v01.s[2 * jj + 1]) +
                   f10 * b2f(v10.s[2 * jj + 1]) + f11 * b2f(v11.s[2 * jj + 1]);
        dw[jj] = (unsigned)f2b(s0) | ((unsigned)f2b(s1) << 16);
      }
      *(uint4*)stg_at(tt, gcs, ppx) = make_uint4(dw[0], dw[1], dw[2], dw[3]);
    }
    __syncthreads();
    // MFMA over the 3 staged taps
#pragma unroll
    for (int tt = 0; tt < 3; ++tt) {
      int t = tc * 3 + tt;
      U16B bf;
      bf.u = *(const uint4*)stg_at(tt, kq * 2 + h, px);
      const u16* wp = wdef + ((size_t)((t * 4 + kq) * 2)) * 512 + lane * 8;
      U16B a0, a1;
      a0.u = *(const uint4*)wp;
      a1.u = *(const uint4*)(wp + 512);
      acc0 = __builtin_amdgcn_mfma_f32_32x32x16_bf16(a0.v, bf.v, acc0, 0, 0, 0);
      acc1 = __builtin_amdgcn_mfma_f32_32x32x16_bf16(a1.v, bf.v, acc1, 0, 0, 0);
    }
    __syncthreads();  // before restage
  }

  // ================= reductions + store =================
  const size_t pixb = (((size_t)(n * 128 + y)) * 128 + px) * 64;
  if (kq != 0) {
#pragma unroll
    for (int i = 0; i < 16; ++i) s_redf[((p2 * 3 + (kq - 1)) * 16 + i) * 64 + lane] = acc0[i];
  }
  __syncthreads();
  if (kq == 0) {
#pragma unroll
    for (int q = 0; q < 4; ++q) {
      int oo = 8 * q + 4 * h;
      float v[4];
#pragma unroll
      for (int r = 0; r < 4; ++r) {
        int i = q * 4 + r;
        v[r] = acc0[i] + s_redf[((p2 * 3 + 0) * 16 + i) * 64 + lane] +
               s_redf[((p2 * 3 + 1) * 16 + i) * 64 + lane] +
               s_redf[((p2 * 3 + 2) * 16 + i) * 64 + lane] + bdef[oo + r];
      }
      ushort4 hh;
      hh.x = f2b(v[0]); hh.y = f2b(v[1]); hh.z = f2b(v[2]); hh.w = f2b(v[3]);
      *(ushort4*)(outH + pixb + oo) = hh;
    }
  }
  __syncthreads();
  if (kq != 0) {
#pragma unroll
    for (int i = 0; i < 16; ++i) s_redf[((p2 * 3 + (kq - 1)) * 16 + i) * 64 + lane] = acc1[i];
  }
  __syncthreads();
  if (kq == 0) {
#pragma unroll
    for (int q = 0; q < 4; ++q) {
      int oo = 32 + 8 * q + 4 * h;
      float v[4];
#pragma unroll
      for (int r = 0; r < 4; ++r) {
        int i = q * 4 + r;
        v[r] = acc1[i] + s_redf[((p2 * 3 + 0) * 16 + i) * 64 + lane] +
               s_redf[((p2 * 3 + 1) * 16 + i) * 64 + lane] +
               s_redf[((p2 * 3 + 2) * 16 + i) * 64 + lane] + bdef[oo + r];
      }
      ushort4 hh;
      hh.x = f2b(v[0]); hh.y = f2b(v[1]); hh.z = f2b(v[2]); hh.w = f2b(v[3]);
      *(ushort4*)(outH + pixb + oo) = hh;
    }
  }
}

// ---------------------------------------------------------------------------
extern "C" void kernel_launch(void* const* d_in, const int* in_sizes, int n_in,
                              void* d_out, int out_size, void* d_ws, size_t ws_size,
                              hipStream_t stream) {
  const float* xd = (const float*)d_in[0];
  const float* xl = (const float*)d_in[1];
  const float* xr = (const float*)d_in[2];
  const float* up_w = (const float*)d_in[3];
  const float* up_b = (const float*)d_in[4];
  const float* offl_w = (const float*)d_in[5];
  const float* offl_b = (const float*)d_in[6];
  const float* dl_w = (const float*)d_in[7];
  const float* dl_b = (const float*)d_in[8];
  const float* offr_w = (const float*)d_in[9];
  const float* offr_b = (const float*)d_in[10];
  const float* dr_w = (const float*)d_in[11];
  const float* dr_b = (const float*)d_in[12];
  const float* cv_w = (const float*)d_in[13];
  const float* cv_b = (const float*)d_in[14];
  const float* rb1_w1 = (const float*)d_in[15];
  const float* rb1_w2 = (const float*)d_in[16];
  const float* rb2_w1 = (const float*)d_in[17];
  const float* rb2_w2 = (const float*)d_in[18];
  const float* rb1_b1 = (const float*)d_in[19];
  const float* rb1_b2 = (const float*)d_in[20];
  const float* rb2_b1 = (const float*)d_in[21];
  const float* rb2_b2 = (const float*)d_in[22];

  float* ws = (float*)d_ws;
  u16* hb = (u16*)(ws + 1769472);
  u16* xlh = hb;                   // 2097152 each
  u16* xrh = hb + 2097152;
  u16* xdph = hb + 4194304;
  u16* xl2h = hb + 6291456;
  u16* xr2h = hb + 8388608;
  u16* t0h = hb + 10485760;
  u16* t1h = hb + 12582912;
  u16* t2h = hb + 14680064;
  u16* t3h = hb + 16777216;
  u16* xdh = hb + 18874368;        // 1048576 (2*64*64*128)
  u16* wcv = hb + 19922944;        // 110592
  u16* wofl = hb + 20033536;       // 55296
  u16* wofr = hb + 20088832;       // 55296
  u16* wr1a = hb + 20144128;       // 36864
  u16* wr1b = hb + 20180992;
  u16* wr2a = hb + 20217856;
  u16* wr2b = hb + 20254720;
  u16* wdl = hb + 20291584;        // 36864
  u16* wdr = hb + 20328448;        // 36864
  u16* wup = hb + 20365312;        // 32768
  float* outp = (float*)d_out;

  hipLaunchKernelGGL(setup_kernel, dim3(2496), dim3(256), 0, stream,
                     dl_w, dr_w, up_w, cv_w, offl_w, offr_w, rb1_w1, rb1_w2,
                     rb2_w1, rb2_w2, wup, wdl, wdr, wcv, wofl, wofr, wr1a,
                     wr1b, wr2a, wr2b, xl, xr, xlh, xrh, xd, xdh);
  hipLaunchKernelGGL(upconv_mf, dim3(128, 2), dim3(1024), 0, stream,
                     xdh, wup, up_b, xdph);
  hipLaunchKernelGGL(deform_fused, dim3(128, 2), dim3(1024), 0, stream,
                     xlh, xrh, xdph, wofl, offl_b, xlh, wdl, dl_b, xl2h);
  hipLaunchKernelGGL(deform_fused, dim3(128, 2), dim3(1024), 0, stream,
                     xl2h, xrh, xdph, wofr, offr_b, xrh, wdr, dr_b, xr2h);
  hipLaunchKernelGGL(mfconv_d<3>, dim3(256, 2, 2), dim3(512), 0, stream,
                     xl2h, xr2h, xdph, wcv, cv_b, (const u16*)nullptr,
                     (float*)nullptr, t0h, 2, 64, 1);
  hipLaunchKernelGGL(mfconv_d<1>, dim3(256, 2, 2), dim3(512), 0, stream,
                     t0h, (const u16*)nullptr, (const u16*)nullptr, wr1a,
                     rb1_b1, (const u16*)nullptr, (float*)nullptr, t1h,
                     2, 64, 1);
  hipLaunchKernelGGL(mfconv_d<1>, dim3(256, 2, 2), dim3(512), 0, stream,
                     t1h, (const u16*)nullptr, (const u16*)nullptr, wr1b,
                     rb1_b2, t0h, (float*)nullptr, t2h, 2, 64, 3);
  hipLaunchKernelGGL(mfconv_d<1>, dim3(256, 2, 2), dim3(512), 0, stream,
                     t2h, (const u16*)nullptr, (const u16*)nullptr, wr2a,
                     rb2_b1, (const u16*)nullptr, (float*)nullptr, t3h,
                     2, 64, 1);
  hipLaunchKernelGGL(mfconv_d<1>, dim3(256, 2, 2), dim3(512), 0, stream,
                     t3h, (const u16*)nullptr, (const u16*)nullptr, wr2b,
                     rb2_b2, t2h, outp, (u16*)nullptr, 2, 64, 3);
}

// Round 14
// 137.246 us; speedup vs baseline: 1.4212x; 1.2625x over previous
//
#include <hip/hip_runtime.h>
#include <math.h>

#define HW 16384

typedef unsigned short u16;
typedef __attribute__((ext_vector_type(8))) short short8;
typedef __attribute__((ext_vector_type(16))) float f32x16;

union U16B {
  uint4 u;
  short8 v;
  u16 s[8];
};

__device__ inline u16 f2b(float f) {
  unsigned u = __float_as_uint(f);
  u += 0x7FFF + ((u >> 16) & 1);
  return (u16)(u >> 16);
}
__device__ inline float b2f(u16 h) {
  return __uint_as_float(((unsigned)h) << 16);
}

// ---------------------------------------------------------------------------
// Weight packing helpers (bf16 per-lane MFMA A-fragments).
// ---------------------------------------------------------------------------
__device__ inline u16 pack_frag(const float* __restrict__ w, int Cin, int O,
                                int OT, int d) {
  int j = d & 7;
  int lane = (d >> 3) & 63;
  int rest = d >> 9;
  int ot = rest % OT; rest /= OT;
  int ks = rest & 3; rest >>= 2;
  int kx = rest % 3; rest /= 3;
  int ky = rest % 3; int s = rest / 3;
  int och = ot * 32 + (lane & 31);
  int ch = s * 64 + ks * 16 + ((lane >> 5) << 3) + j;
  if (och >= O) return 0;
  return f2b(w[((size_t)och * Cin + ch) * 9 + ky * 3 + kx]);
}

__device__ inline u16 pack_def(const float* __restrict__ w, int d) {
  int j = d & 7;
  int lane = (d >> 3) & 63;
  int g = d >> 9;
  int ot = g & 1;
  int t = g >> 1;
  int ks = t & 3;
  int k = t >> 2;
  int och = ot * 32 + (lane & 31);
  int c = ks * 16 + ((lane >> 5) << 3) + j;
  return f2b(w[((size_t)och * 64 + c) * 9 + k]);
}

__device__ inline u16 pack_up(const float* __restrict__ w, int d) {
  int j = d & 7;
  int lane = (d >> 3) & 63;
  int g = d >> 9;
  int ot = g & 1;
  int rest = g >> 1;
  int ks = rest & 7;
  int t = rest >> 3;
  int och = ot * 32 + (lane & 31);
  int ci = ks * 16 + ((lane >> 5) << 3) + j;
  return f2b(w[((size_t)och * 128 + ci) * 4 + t]);
}

// ---------------------------------------------------------------------------
// setup_kernel (unchanged — validated)
// ---------------------------------------------------------------------------
__global__ __launch_bounds__(256) void setup_kernel(
    const float* __restrict__ dl_w, const float* __restrict__ dr_w,
    const float* __restrict__ up_w, const float* __restrict__ cv_w,
    const float* __restrict__ offl_w, const float* __restrict__ offr_w,
    const float* __restrict__ r1a, const float* __restrict__ r1b,
    const float* __restrict__ r2a, const float* __restrict__ r2b,
    u16* __restrict__ wup, u16* __restrict__ wdl, u16* __restrict__ wdr,
    u16* __restrict__ wcv, u16* __restrict__ wofl, u16* __restrict__ wofr,
    u16* __restrict__ wr1a, u16* __restrict__ wr1b,
    u16* __restrict__ wr2a, u16* __restrict__ wr2b,
    const float* __restrict__ xl, const float* __restrict__ xr,
    u16* __restrict__ xlh, u16* __restrict__ xrh,
    const float* __restrict__ xd, u16* __restrict__ xdh) {
  __shared__ float sT[8448];
  int tid = threadIdx.x;
  int b = blockIdx.x;
  if (b < 1856) {
    int d = b * 256 + tid;
    if (d < 32768) { wup[d] = pack_up(up_w, d); return; }
    d -= 32768;
    if (d < 36864) { wdl[d] = pack_def(dl_w, d); return; }
    d -= 36864;
    if (d < 36864) { wdr[d] = pack_def(dr_w, d); return; }
    d -= 36864;
    if (d < 110592) { wcv[d] = pack_frag(cv_w, 192, 64, 2, d); return; }
    d -= 110592;
    if (d < 55296) { wofl[d] = pack_frag(offl_w, 192, 27, 1, d); return; }
    d -= 55296;
    if (d < 55296) { wofr[d] = pack_frag(offr_w, 192, 27, 1, d); return; }
    d -= 55296;
    if (d < 36864) { wr1a[d] = pack_frag(r1a, 64, 64, 2, d); return; }
    d -= 36864;
    if (d < 36864) { wr1b[d] = pack_frag(r1b, 64, 64, 2, d); return; }
    d -= 36864;
    if (d < 36864) { wr2a[d] = pack_frag(r2a, 64, 64, 2, d); return; }
    d -= 36864;
    if (d < 36864) { wr2b[d] = pack_frag(r2b, 64, 64, 2, d); return; }
    return;
  }
  b -= 1856;
  if (b < 512) {
    int y = b & 127;
    int pid = b >> 7;
    const float* src = (pid >> 1) ? xr : xl;
    u16* dst = (pid >> 1) ? xrh : xlh;
    int n = pid & 1;
#pragma unroll
    for (int i = 0; i < 8; ++i) {
      int q = tid + i * 256;
      int ch = q >> 5, pxq = q & 31;
      float4 v = *(const float4*)(src + ((size_t)(n * 64 + ch)) * HW + y * 128 + pxq * 4);
      *(float4*)&sT[ch * 132 + pxq * 4] = v;
    }
    __syncthreads();
    int px = tid >> 1, half = tid & 1;
    u16* op = dst + (((size_t)(n * 128 + y)) * 128 + px) * 64 + half * 32;
#pragma unroll
    for (int c = 0; c < 4; ++c) {
      uint4 v;
      int ob = (half * 32 + c * 8);
      v.x = (unsigned)f2b(sT[(ob + 0) * 132 + px]) | ((unsigned)f2b(sT[(ob + 1) * 132 + px]) << 16);
      v.y = (unsigned)f2b(sT[(ob + 2) * 132 + px]) | ((unsigned)f2b(sT[(ob + 3) * 132 + px]) << 16);
      v.z = (unsigned)f2b(sT[(ob + 4) * 132 + px]) | ((unsigned)f2b(sT[(ob + 5) * 132 + px]) << 16);
      v.w = (unsigned)f2b(sT[(ob + 6) * 132 + px]) | ((unsigned)f2b(sT[(ob + 7) * 132 + px]) << 16);
      *(uint4*)(op + c * 8) = v;
    }
    return;
  }
  b -= 512;
  {
    int r = b & 63;
    int n = b >> 6;
#pragma unroll
    for (int i = 0; i < 8; ++i) {
      int q = tid + i * 256;
      int ch = q >> 4, col4 = q & 15;
      float4 v = *(const float4*)(xd + ((size_t)(n * 128 + ch) * 64 + r) * 64 + col4 * 4);
      *(float4*)&sT[ch * 66 + col4 * 4] = v;
    }
    __syncthreads();
#pragma unroll
    for (int i = 0; i < 4; ++i) {
      int q = tid + i * 256;
      int col = q >> 4, cho = q & 15;
      uint4 v;
      int cb = cho * 8;
      v.x = (unsigned)f2b(sT[(cb + 0) * 66 + col]) | ((unsigned)f2b(sT[(cb + 1) * 66 + col]) << 16);
      v.y = (unsigned)f2b(sT[(cb + 2) * 66 + col]) | ((unsigned)f2b(sT[(cb + 3) * 66 + col]) << 16);
      v.z = (unsigned)f2b(sT[(cb + 4) * 66 + col]) | ((unsigned)f2b(sT[(cb + 5) * 66 + col]) << 16);
      v.w = (unsigned)f2b(sT[(cb + 6) * 66 + col]) | ((unsigned)f2b(sT[(cb + 7) * 66 + col]) << 16);
      *(uint4*)(xdh + (((size_t)(n * 64 + r)) * 64 + col) * 128 + cb) = v;
    }
  }
}

// ---------------------------------------------------------------------------
// Upsample + 2x2 conv (unchanged — validated)
// ---------------------------------------------------------------------------
__global__ __launch_bounds__(1024) void upconv_mf(
    const u16* __restrict__ xdh, const u16* __restrict__ wup,
    const float* __restrict__ bias, u16* __restrict__ outH) {
  __shared__ float s_red[4][3][16][64];
  const int tid = threadIdx.x;
  const int lane = tid & 63;
  const int w = tid >> 6;
  const int p2 = w >> 2;
  const int t = w & 3;
  const int y = blockIdx.x;
  const int n = blockIdx.y;
  const int px = (p2 << 5) + (lane & 31);
  const int h = lane >> 5;

  f32x16 acc0, acc1;
#pragma unroll
  for (int i = 0; i < 16; ++i) { acc0[i] = 0.f; acc1[i] = 0.f; }

  const u16* xb = xdh + ((size_t)n * 64 * 64) * 128;
  const int ty = t >> 1, tx = t & 1;
  const int row = min((y + ty) >> 1, 63);
  const int col = min((px + tx) >> 1, 63);
  const u16* src = xb + ((size_t)(row * 64 + col)) * 128;
#pragma unroll
  for (int ks = 0; ks < 8; ++ks) {
    U16B bf;
    bf.u = *(const uint4*)(src + ks * 16 + h * 8);
    const u16* wp = wup + ((size_t)((t * 8 + ks) * 2)) * 512 + lane * 8;
    U16B a0, a1;
    a0.u = *(const uint4*)wp;
    a1.u = *(const uint4*)(wp + 512);
    acc0 = __builtin_amdgcn_mfma_f32_32x32x16_bf16(a0.v, bf.v, acc0, 0, 0, 0);
    acc1 = __builtin_amdgcn_mfma_f32_32x32x16_bf16(a1.v, bf.v, acc1, 0, 0, 0);
  }

  const bool zero = (y == 127) || (px == 127);
  const size_t pixb = (((size_t)(n * 128 + y)) * 128 + px) * 64;

  if (t != 0) {
#pragma unroll
    for (int i = 0; i < 16; ++i) s_red[p2][t - 1][i][lane] = acc0[i];
  }
  __syncthreads();
  if (t == 0) {
#pragma unroll
    for (int q = 0; q < 4; ++q) {
      int oo = 8 * q + 4 * h;
      float v[4];
#pragma unroll
      for (int r = 0; r < 4; ++r) {
        int i = q * 4 + r;
        float s = acc0[i] + s_red[p2][0][i][lane] + s_red[p2][1][i][lane] +
                  s_red[p2][2][i][lane];
        v[r] = zero ? 0.f : (s + bias[oo + r]);
      }
      ushort4 hh;
      hh.x = f2b(v[0]); hh.y = f2b(v[1]); hh.z = f2b(v[2]); hh.w = f2b(v[3]);
      *(ushort4*)(outH + pixb + oo) = hh;
    }
  }
  __syncthreads();
  if (t != 0) {
#pragma unroll
    for (int i = 0; i < 16; ++i) s_red[p2][t - 1][i][lane] = acc1[i];
  }
  __syncthreads();
  if (t == 0) {
#pragma unroll
    for (int q = 0; q < 4; ++q) {
      int oo = 32 + 8 * q + 4 * h;
      float v[4];
#pragma unroll
      for (int r = 0; r < 4; ++r) {
        int i = q * 4 + r;
        float s = acc1[i] + s_red[p2][0][i][lane] + s_red[p2][1][i][lane] +
                  s_red[p2][2][i][lane];
        v[r] = zero ? 0.f : (s + bias[oo + r]);
      }
      ushort4 hh;
      hh.x = f2b(v[0]); hh.y = f2b(v[1]); hh.z = f2b(v[2]); hh.w = f2b(v[3]);
      *(ushort4*)(outH + pixb + oo) = hh;
    }
  }
}

// ---------------------------------------------------------------------------
// MFMA 3x3 conv with FULL-LINE staged loads (deform_fused phase-1 structure).
// Block = one row (128 px), 1024 thr = 16 waves = 4 px-tiles x 4 ks-quarters.
// Per segment: stage rows y-1..y+1 coalesced (lane = 8px x 8slices) into
// stg[ky][cg][130][8]; each wave 9 B-frags via ds_read, both ot accumulated.
// Two-round 4-way LDS reduction. mode: 1=relu, 3=+residual. outF=fp32 NCHW.
// ---------------------------------------------------------------------------
template <int NSEG>
__global__ __launch_bounds__(1024) void mfconv_s(
    const u16* __restrict__ in0, const u16* __restrict__ in1,
    const u16* __restrict__ in2, const u16* __restrict__ wpk,
    const float* __restrict__ bias, const u16* __restrict__ resh,
    float* __restrict__ outF, u16* __restrict__ outH, int mode) {
  __shared__ __align__(16) unsigned char s_un[49920];
  u16* stg = (u16*)s_un;            // [ky<3][cg<8][130][8ch]
  float* s_redf = (float*)s_un;     // [p2<4][3][16][64]

  const int tid = threadIdx.x;
  const int lane = tid & 63;
  const int w = tid >> 6;
  const int p2 = w >> 2;
  const int kq = w & 3;
  const int y = blockIdx.x;
  const int n = blockIdx.y;
  const int px = (p2 << 5) + (lane & 31);
  const int h = lane >> 5;
  const int gpx = lane >> 3;
  const int gcs = lane & 7;

  auto stg_at = [&](int e, int cg, int p) -> u16* {
    return stg + (((e * 8 + cg) * 130 + p) << 3);
  };

  f32x16 acc0, acc1;
#pragma unroll
  for (int i = 0; i < 16; ++i) { acc0[i] = 0.f; acc1[i] = 0.f; }

  for (int s = 0; s < NSEG; ++s) {
    const u16* sp = (s == 0) ? in0 : ((s == 1) ? in1 : in2);
    const u16* bn = sp + ((size_t)n * 128) * 128 * 64;
    // stage 3 rows: 48 units (ky, g), 3 per wave
    for (int i = w; i < 48; i += 16) {
      int ky = i >> 4, g = i & 15;
      int row = y + ky - 1;
      int ppx = g * 8 + gpx;
      uint4 v = make_uint4(0, 0, 0, 0);
      if ((unsigned)row < 128u)
        v = *(const uint4*)(bn + (size_t)row * (128 * 64) + (size_t)ppx * 64 + gcs * 8);
      *(uint4*)stg_at(ky, gcs, ppx) = v;
    }
    __syncthreads();
#pragma unroll
    for (int ky = 0; ky < 3; ++ky) {
#pragma unroll
      for (int kx = 0; kx < 3; ++kx) {
        int pxc = px + kx - 1;
        bool valid = (unsigned)pxc < 128u;
        int pxcc = min(max(pxc, 0), 127);
        U16B bf;
        bf.u = *(const uint4*)stg_at(ky, kq * 2 + h, pxcc);
        if (!valid) bf.u = make_uint4(0, 0, 0, 0);
        const u16* wp = wpk +
            ((size_t)((((s * 3 + ky) * 3 + kx) * 4 + kq) * 2)) * 512 + lane * 8;
        U16B a0, a1;
        a0.u = *(const uint4*)wp;
        a1.u = *(const uint4*)(wp + 512);
        acc0 = __builtin_amdgcn_mfma_f32_32x32x16_bf16(a0.v, bf.v, acc0, 0, 0, 0);
        acc1 = __builtin_amdgcn_mfma_f32_32x32x16_bf16(a1.v, bf.v, acc1, 0, 0, 0);
      }
    }
    __syncthreads();  // before restage / union reuse
  }

  const size_t pixb = ((size_t)(n * 128 + y)) * 128 + px;

  // round 1: och 0..31 (acc0)
  if (kq != 0) {
#pragma unroll
    for (int i = 0; i < 16; ++i)
      s_redf[((p2 * 3 + (kq - 1)) * 16 + i) * 64 + lane] = acc0[i];
  }
  __syncthreads();
  if (kq == 0) {
#pragma unroll
    for (int q = 0; q < 4; ++q) {
      int oo = 8 * q + 4 * h;
      float v[4];
#pragma unroll
      for (int r = 0; r < 4; ++r) {
        int i = q * 4 + r;
        v[r] = acc0[i] + s_redf[((p2 * 3 + 0) * 16 + i) * 64 + lane] +
               s_redf[((p2 * 3 + 1) * 16 + i) * 64 + lane] +
               s_redf[((p2 * 3 + 2) * 16 + i) * 64 + lane] + bias[oo + r];
      }
      if (mode == 1) {
#pragma unroll
        for (int r = 0; r < 4; ++r) v[r] = fmaxf(v[r], 0.f);
      } else if (mode == 3) {
        ushort4 rv = *(const ushort4*)(resh + pixb * 64 + oo);
        v[0] += b2f(rv.x); v[1] += b2f(rv.y); v[2] += b2f(rv.z); v[3] += b2f(rv.w);
      }
      if (outH) {
        ushort4 hh;
        hh.x = f2b(v[0]); hh.y = f2b(v[1]); hh.z = f2b(v[2]); hh.w = f2b(v[3]);
        *(ushort4*)(outH + pixb * 64 + oo) = hh;
      } else {
#pragma unroll
        for (int r = 0; r < 4; ++r)
          outF[((size_t)(n * 64 + oo + r)) * HW + y * 128 + px] = v[r];
      }
    }
  }
  __syncthreads();
  // round 2: och 32..63 (acc1)
  if (kq != 0) {
#pragma unroll
    for (int i = 0; i < 16; ++i)
      s_redf[((p2 * 3 + (kq - 1)) * 16 + i) * 64 + lane] = acc1[i];
  }
  __syncthreads();
  if (kq == 0) {
#pragma unroll
    for (int q = 0; q < 4; ++q) {
      int oo = 32 + 8 * q + 4 * h;
      float v[4];
#pragma unroll
      for (int r = 0; r < 4; ++r) {
        int i = q * 4 + r;
        v[r] = acc1[i] + s_redf[((p2 * 3 + 0) * 16 + i) * 64 + lane] +
               s_redf[((p2 * 3 + 1) * 16 + i) * 64 + lane] +
               s_redf[((p2 * 3 + 2) * 16 + i) * 64 + lane] + bias[oo + r];
      }
      if (mode == 1) {
#pragma unroll
        for (int r = 0; r < 4; ++r) v[r] = fmaxf(v[r], 0.f);
      } else if (mode == 3) {
        ushort4 rv = *(const ushort4*)(resh + pixb * 64 + oo);
        v[0] += b2f(rv.x); v[1] += b2f(rv.y); v[2] += b2f(rv.z); v[3] += b2f(rv.w);
      }
      if (outH) {
        ushort4 hh;
        hh.x = f2b(v[0]); hh.y = f2b(v[1]); hh.z = f2b(v[2]); hh.w = f2b(v[3]);
        *(ushort4*)(outH + pixb * 64 + oo) = hh;
      } else {
#pragma unroll
        for (int r = 0; r < 4; ++r)
          outF[((size_t)(n * 64 + oo + r)) * HW + y * 128 + px] = v[r];
      }
    }
  }
}

// ---------------------------------------------------------------------------
// Fused offset-conv + deformable conv (unchanged from R12 — validated).
// ---------------------------------------------------------------------------
__global__ __launch_bounds__(1024) void deform_fused(
    const u16* __restrict__ in0, const u16* __restrict__ in1,
    const u16* __restrict__ in2, const u16* __restrict__ woff,
    const float* __restrict__ boff, const u16* __restrict__ xh,
    const u16* __restrict__ wdef, const float* __restrict__ bdef,
    u16* __restrict__ outH) {
  __shared__ float s_off[27][128];
  __shared__ __align__(16) unsigned char s_un[49920];
  u16* stg = (u16*)s_un;
  float* s_redf = (float*)s_un;

  const int tid = threadIdx.x;
  const int lane = tid & 63;
  const int w = tid >> 6;
  const int p2 = w >> 2;
  const int kq = w & 3;
  const int y = blockIdx.x;
  const int n = blockIdx.y;
  const int px = (p2 << 5) + (lane & 31);
  const int h = lane >> 5;
  const int gpx = lane >> 3;
  const int gcs = lane & 7;

  auto stg_at = [&](int e, int cg, int p) -> u16* {
    return stg + (((e * 8 + cg) * 130 + p) << 3);
  };

  // ================= Phase 1: offset conv =================
  f32x16 acc;
#pragma unroll
  for (int i = 0; i < 16; ++i) acc[i] = 0.f;

  for (int s = 0; s < 3; ++s) {
    const u16* sp = (s == 0) ? in0 : ((s == 1) ? in1 : in2);
    const u16* bn = sp + ((size_t)n * 128) * 128 * 64;
    for (int i = w; i < 48; i += 16) {
      int ky = i >> 4, g = i & 15;
      int row = y + ky - 1;
      int ppx = g * 8 + gpx;
      uint4 v = make_uint4(0, 0, 0, 0);
      if ((unsigned)row < 128u)
        v = *(const uint4*)(bn + (size_t)row * (128 * 64) + (size_t)ppx * 64 + gcs * 8);
      *(uint4*)stg_at(ky, gcs, ppx) = v;
    }
    __syncthreads();
#pragma unroll
    for (int ky = 0; ky < 3; ++ky) {
#pragma unroll
      for (int kx = 0; kx < 3; ++kx) {
        int pxc = px + kx - 1;
        bool valid = (unsigned)pxc < 128u;
        int pxcc = min(max(pxc, 0), 127);
        U16B bf;
        bf.u = *(const uint4*)stg_at(ky, kq * 2 + h, pxcc);
        if (!valid) bf.u = make_uint4(0, 0, 0, 0);
        U16B a;
        a.u = *(const uint4*)(woff +
              ((size_t)(((s * 3 + ky) * 3 + kx) * 4 + kq)) * 512 + lane * 8);
        acc = __builtin_amdgcn_mfma_f32_32x32x16_bf16(a.v, bf.v, acc, 0, 0, 0);
      }
    }
    __syncthreads();
  }

  if (kq != 0) {
#pragma unroll
    for (int i = 0; i < 16; ++i) s_redf[((p2 * 3 + (kq - 1)) * 16 + i) * 64 + lane] = acc[i];
  }
  __syncthreads();
  if (kq == 0) {
#pragma unroll
    for (int q = 0; q < 4; ++q) {
#pragma unroll
      for (int r = 0; r < 4; ++r) {
        int och = 8 * q + 4 * h + r;
        if (och < 27) {
          int i = q * 4 + r;
          float v = acc[i] + s_redf[((p2 * 3 + 0) * 16 + i) * 64 + lane] +
                    s_redf[((p2 * 3 + 1) * 16 + i) * 64 + lane] +
                    s_redf[((p2 * 3 + 2) * 16 + i) * 64 + lane] + boff[och];
          if (och >= 18) v = 1.f / (1.f + expf(-v));
          s_off[och][px] = v;
        }
      }
    }
  }
  __syncthreads();

  // ================= Phase 2: deform =================
  f32x16 acc0, acc1;
#pragma unroll
  for (int i = 0; i < 16; ++i) { acc0[i] = 0.f; acc1[i] = 0.f; }

  const u16* xb = xh + ((size_t)n * HW) * 64;

  for (int tc = 0; tc < 3; ++tc) {
    for (int i = w; i < 48; i += 16) {
      int tt = i >> 4, g = i & 15;
      int t = tc * 3 + tt;
      int ppx = g * 8 + gpx;
      int ky = t / 3 - 1, kx = t % 3 - 1;
      float dy = s_off[2 * t][ppx];
      float dx = s_off[2 * t + 1][ppx];
      float m = s_off[18 + t][ppx];
      float py = dy + (float)(y + ky);
      float pxf = dx + (float)(ppx + kx);
      float fy = floorf(py), fxx = floorf(pxf);
      float wy = py - fy, wx = pxf - fxx;
      int iy0 = (int)fy, ix0 = (int)fxx;
      bool vy0 = (unsigned)iy0 < 128u, vy1 = (unsigned)(iy0 + 1) < 128u;
      bool vx0 = (unsigned)ix0 < 128u, vx1 = (unsigned)(ix0 + 1) < 128u;
      float omwy = 1.f - wy, omwx = 1.f - wx;
      float f00 = (vy0 && vx0) ? omwy * omwx * m : 0.f;
      float f01 = (vy0 && vx1) ? omwy * wx * m : 0.f;
      float f10 = (vy1 && vx0) ? wy * omwx * m : 0.f;
      float f11 = (vy1 && vx1) ? wy * wx * m : 0.f;
      int y0c = min(max(iy0, 0), 127), y1c = min(max(iy0 + 1, 0), 127);
      int x0c = min(max(ix0, 0), 127), x1c = min(max(ix0 + 1, 0), 127);
      U16B v00, v01, v10, v11;
      v00.u = *(const uint4*)(xb + ((size_t)(y0c * 128 + x0c)) * 64 + gcs * 8);
      v01.u = *(const uint4*)(xb + ((size_t)(y0c * 128 + x1c)) * 64 + gcs * 8);
      v10.u = *(const uint4*)(xb + ((size_t)(y1c * 128 + x0c)) * 64 + gcs * 8);
      v11.u = *(const uint4*)(xb + ((size_t)(y1c * 128 + x1c)) * 64 + gcs * 8);
      unsigned dw[4];
#pragma unroll
      for (int jj = 0; jj < 4; ++jj) {
        float s0 = f00 * b2f(v00.s[2 * jj]) + f01 * b2f(v01.s[2 * jj]) +
                   f10 * b2f(v10.s[2 * jj]) + f11 * b2f(v11.s[2 * jj]);
        float s1 = f00 * b2f(v00.s[2 * jj + 1]) + f01 * b2f(v01.s[2 * jj + 1]) +
                   f10 * b2f(v10.s[2 * jj + 1]) + f11 * b2f(v11.s[2 * jj + 1]);
        dw[jj] = (unsigned)f2b(s0) | ((unsigned)f2b(s1) << 16);
      }
      *(uint4*)stg_at(tt, gcs, ppx) = make_uint4(dw[0], dw[1], dw[2], dw[3]);
    }
    __syncthreads();
#pragma unroll
    for (int tt = 0; tt < 3; ++tt) {
      int t = tc * 3 + tt;
      U16B bf;
      bf.u = *(const uint4*)stg_at(tt, kq * 2 + h, px);
      const u16* wp = wdef + ((size_t)((t * 4 + kq) * 2)) * 512 + lane * 8;
      U16B a0, a1;
      a0.u = *(const uint4*)wp;
      a1.u = *(const uint4*)(wp + 512);
      acc0 = __builtin_amdgcn_mfma_f32_32x32x16_bf16(a0.v, bf.v, acc0, 0, 0, 0);
      acc1 = __builtin_amdgcn_mfma_f32_32x32x16_bf16(a1.v, bf.v, acc1, 0, 0, 0);
    }
    __syncthreads();
  }

  const size_t pixb = (((size_t)(n * 128 + y)) * 128 + px) * 64;
  if (kq != 0) {
#pragma unroll
    for (int i = 0; i < 16; ++i) s_redf[((p2 * 3 + (kq - 1)) * 16 + i) * 64 + lane] = acc0[i];
  }
  __syncthreads();
  if (kq == 0) {
#pragma unroll
    for (int q = 0; q < 4; ++q) {
      int oo = 8 * q + 4 * h;
      float v[4];
#pragma unroll
      for (int r = 0; r < 4; ++r) {
        int i = q * 4 + r;
        v[r] = acc0[i] + s_redf[((p2 * 3 + 0) * 16 + i) * 64 + lane] +
               s_redf[((p2 * 3 + 1) * 16 + i) * 64 + lane] +
               s_redf[((p2 * 3 + 2) * 16 + i) * 64 + lane] + bdef[oo + r];
      }
      ushort4 hh;
      hh.x = f2b(v[0]); hh.y = f2b(v[1]); hh.z = f2b(v[2]); hh.w = f2b(v[3]);
      *(ushort4*)(outH + pixb + oo) = hh;
    }
  }
  __syncthreads();
  if (kq != 0) {
#pragma unroll
    for (int i = 0; i < 16; ++i) s_redf[((p2 * 3 + (kq - 1)) * 16 + i) * 64 + lane] = acc1[i];
  }
  __syncthreads();
  if (kq == 0) {
#pragma unroll
    for (int q = 0; q < 4; ++q) {
      int oo = 32 + 8 * q + 4 * h;
      float v[4];
#pragma unroll
      for (int r = 0; r < 4; ++r) {
        int i = q * 4 + r;
        v[r] = acc1[i] + s_redf[((p2 * 3 + 0) * 16 + i) * 64 + lane] +
               s_redf[((p2 * 3 + 1) * 16 + i) * 64 + lane] +
               s_redf[((p2 * 3 + 2) * 16 + i) * 64 + lane] + bdef[oo + r];
      }
      ushort4 hh;
      hh.x = f2b(v[0]); hh.y = f2b(v[1]); hh.z = f2b(v[2]); hh.w = f2b(v[3]);
      *(ushort4*)(outH + pixb + oo) = hh;
    }
  }
}

// ---------------------------------------------------------------------------
extern "C" void kernel_launch(void* const* d_in, const int* in_sizes, int n_in,
                              void* d_out, int out_size, void* d_ws, size_t ws_size,
                              hipStream_t stream) {
  const float* xd = (const float*)d_in[0];
  const float* xl = (const float*)d_in[1];
  const float* xr = (const float*)d_in[2];
  const float* up_w = (const float*)d_in[3];
  const float* up_b = (const float*)d_in[4];
  const float* offl_w = (const float*)d_in[5];
  const float* offl_b = (const float*)d_in[6];
  const float* dl_w = (const float*)d_in[7];
  const float* dl_b = (const float*)d_in[8];
  const float* offr_w = (const float*)d_in[9];
  const float* offr_b = (const float*)d_in[10];
  const float* dr_w = (const float*)d_in[11];
  const float* dr_b = (const float*)d_in[12];
  const float* cv_w = (const float*)d_in[13];
  const float* cv_b = (const float*)d_in[14];
  const float* rb1_w1 = (const float*)d_in[15];
  const float* rb1_w2 = (const float*)d_in[16];
  const float* rb2_w1 = (const float*)d_in[17];
  const float* rb2_w2 = (const float*)d_in[18];
  const float* rb1_b1 = (const float*)d_in[19];
  const float* rb1_b2 = (const float*)d_in[20];
  const float* rb2_b1 = (const float*)d_in[21];
  const float* rb2_b2 = (const float*)d_in[22];

  float* ws = (float*)d_ws;
  u16* hb = (u16*)(ws + 1769472);
  u16* xlh = hb;                   // 2097152 each
  u16* xrh = hb + 2097152;
  u16* xdph = hb + 4194304;
  u16* xl2h = hb + 6291456;
  u16* xr2h = hb + 8388608;
  u16* t0h = hb + 10485760;
  u16* t1h = hb + 12582912;
  u16* t2h = hb + 14680064;
  u16* t3h = hb + 16777216;
  u16* xdh = hb + 18874368;        // 1048576 (2*64*64*128)
  u16* wcv = hb + 19922944;        // 110592
  u16* wofl = hb + 20033536;       // 55296
  u16* wofr = hb + 20088832;       // 55296
  u16* wr1a = hb + 20144128;       // 36864
  u16* wr1b = hb + 20180992;
  u16* wr2a = hb + 20217856;
  u16* wr2b = hb + 20254720;
  u16* wdl = hb + 20291584;        // 36864
  u16* wdr = hb + 20328448;        // 36864
  u16* wup = hb + 20365312;        // 32768
  float* outp = (float*)d_out;

  hipLaunchKernelGGL(setup_kernel, dim3(2496), dim3(256), 0, stream,
                     dl_w, dr_w, up_w, cv_w, offl_w, offr_w, rb1_w1, rb1_w2,
                     rb2_w1, rb2_w2, wup, wdl, wdr, wcv, wofl, wofr, wr1a,
                     wr1b, wr2a, wr2b, xl, xr, xlh, xrh, xd, xdh);
  hipLaunchKernelGGL(upconv_mf, dim3(128, 2), dim3(1024), 0, stream,
                     xdh, wup, up_b, xdph);
  hipLaunchKernelGGL(deform_fused, dim3(128, 2), dim3(1024), 0, stream,
                     xlh, xrh, xdph, wofl, offl_b, xlh, wdl, dl_b, xl2h);
  hipLaunchKernelGGL(deform_fused, dim3(128, 2), dim3(1024), 0, stream,
                     xl2h, xrh, xdph, wofr, offr_b, xrh, wdr, dr_b, xr2h);
  hipLaunchKernelGGL(mfconv_s<3>, dim3(128, 2), dim3(1024), 0, stream,
                     xl2h, xr2h, xdph, wcv, cv_b, (const u16*)nullptr,
                     (float*)nullptr, t0h, 1);
  hipLaunchKernelGGL(mfconv_s<1>, dim3(128, 2), dim3(1024), 0, stream,
                     t0h, (const u16*)nullptr, (const u16*)nullptr, wr1a,
                     rb1_b1, (const u16*)nullptr, (float*)nullptr, t1h, 1);
  hipLaunchKernelGGL(mfconv_s<1>, dim3(128, 2), dim3(1024), 0, stream,
                     t1h, (const u16*)nullptr, (const u16*)nullptr, wr1b,
                     rb1_b2, t0h, (float*)nullptr, t2h, 3);
  hipLaunchKernelGGL(mfconv_s<1>, dim3(128, 2), dim3(1024), 0, stream,
                     t2h, (const u16*)nullptr, (const u16*)nullptr, wr2a,
                     rb2_b1, (const u16*)nullptr, (float*)nullptr, t3h, 1);
  hipLaunchKernelGGL(mfconv_s<1>, dim3(128, 2), dim3(1024), 0, stream,
                     t3h, (const u16*)nullptr, (const u16*)nullptr, wr2b,
                     rb2_b2, t2h, outp, (u16*)nullptr, 3);
}

// Round 15
// 132.398 us; speedup vs baseline: 1.4733x; 1.0366x over previous
//
#include <hip/hip_runtime.h>
#include <math.h>

#define HW 16384

typedef unsigned short u16;
typedef __attribute__((ext_vector_type(8))) short short8;
typedef __attribute__((ext_vector_type(16))) float f32x16;

union U16B {
  uint4 u;
  short8 v;
  u16 s[8];
};

__device__ inline u16 f2b(float f) {
  unsigned u = __float_as_uint(f);
  u += 0x7FFF + ((u >> 16) & 1);
  return (u16)(u >> 16);
}
__device__ inline float b2f(u16 h) {
  return __uint_as_float(((unsigned)h) << 16);
}

// ---------------------------------------------------------------------------
// Weight packing helpers (bf16 per-lane MFMA A-fragments).
// ---------------------------------------------------------------------------
__device__ inline u16 pack_frag(const float* __restrict__ w, int Cin, int O,
                                int OT, int d) {
  int j = d & 7;
  int lane = (d >> 3) & 63;
  int rest = d >> 9;
  int ot = rest % OT; rest /= OT;
  int ks = rest & 3; rest >>= 2;
  int kx = rest % 3; rest /= 3;
  int ky = rest % 3; int s = rest / 3;
  int och = ot * 32 + (lane & 31);
  int ch = s * 64 + ks * 16 + ((lane >> 5) << 3) + j;
  if (och >= O) return 0;
  return f2b(w[((size_t)och * Cin + ch) * 9 + ky * 3 + kx]);
}

__device__ inline u16 pack_def(const float* __restrict__ w, int d) {
  int j = d & 7;
  int lane = (d >> 3) & 63;
  int g = d >> 9;
  int ot = g & 1;
  int t = g >> 1;
  int ks = t & 3;
  int k = t >> 2;
  int och = ot * 32 + (lane & 31);
  int c = ks * 16 + ((lane >> 5) << 3) + j;
  return f2b(w[((size_t)och * 64 + c) * 9 + k]);
}

__device__ inline u16 pack_up(const float* __restrict__ w, int d) {
  int j = d & 7;
  int lane = (d >> 3) & 63;
  int g = d >> 9;
  int ot = g & 1;
  int rest = g >> 1;
  int ks = rest & 7;
  int t = rest >> 3;
  int och = ot * 32 + (lane & 31);
  int ci = ks * 16 + ((lane >> 5) << 3) + j;
  return f2b(w[((size_t)och * 128 + ci) * 4 + t]);
}

// ---------------------------------------------------------------------------
// setup_kernel (unchanged — validated)
// ---------------------------------------------------------------------------
__global__ __launch_bounds__(256) void setup_kernel(
    const float* __restrict__ dl_w, const float* __restrict__ dr_w,
    const float* __restrict__ up_w, const float* __restrict__ cv_w,
    const float* __restrict__ offl_w, const float* __restrict__ offr_w,
    const float* __restrict__ r1a, const float* __restrict__ r1b,
    const float* __restrict__ r2a, const float* __restrict__ r2b,
    u16* __restrict__ wup, u16* __restrict__ wdl, u16* __restrict__ wdr,
    u16* __restrict__ wcv, u16* __restrict__ wofl, u16* __restrict__ wofr,
    u16* __restrict__ wr1a, u16* __restrict__ wr1b,
    u16* __restrict__ wr2a, u16* __restrict__ wr2b,
    const float* __restrict__ xl, const float* __restrict__ xr,
    u16* __restrict__ xlh, u16* __restrict__ xrh,
    const float* __restrict__ xd, u16* __restrict__ xdh) {
  __shared__ float sT[8448];
  int tid = threadIdx.x;
  int b = blockIdx.x;
  if (b < 1856) {
    int d = b * 256 + tid;
    if (d < 32768) { wup[d] = pack_up(up_w, d); return; }
    d -= 32768;
    if (d < 36864) { wdl[d] = pack_def(dl_w, d); return; }
    d -= 36864;
    if (d < 36864) { wdr[d] = pack_def(dr_w, d); return; }
    d -= 36864;
    if (d < 110592) { wcv[d] = pack_frag(cv_w, 192, 64, 2, d); return; }
    d -= 110592;
    if (d < 55296) { wofl[d] = pack_frag(offl_w, 192, 27, 1, d); return; }
    d -= 55296;
    if (d < 55296) { wofr[d] = pack_frag(offr_w, 192, 27, 1, d); return; }
    d -= 55296;
    if (d < 36864) { wr1a[d] = pack_frag(r1a, 64, 64, 2, d); return; }
    d -= 36864;
    if (d < 36864) { wr1b[d] = pack_frag(r1b, 64, 64, 2, d); return; }
    d -= 36864;
    if (d < 36864) { wr2a[d] = pack_frag(r2a, 64, 64, 2, d); return; }
    d -= 36864;
    if (d < 36864) { wr2b[d] = pack_frag(r2b, 64, 64, 2, d); return; }
    return;
  }
  b -= 1856;
  if (b < 512) {
    int y = b & 127;
    int pid = b >> 7;
    const float* src = (pid >> 1) ? xr : xl;
    u16* dst = (pid >> 1) ? xrh : xlh;
    int n = pid & 1;
#pragma unroll
    for (int i = 0; i < 8; ++i) {
      int q = tid + i * 256;
      int ch = q >> 5, pxq = q & 31;
      float4 v = *(const float4*)(src + ((size_t)(n * 64 + ch)) * HW + y * 128 + pxq * 4);
      *(float4*)&sT[ch * 132 + pxq * 4] = v;
    }
    __syncthreads();
    int px = tid >> 1, half = tid & 1;
    u16* op = dst + (((size_t)(n * 128 + y)) * 128 + px) * 64 + half * 32;
#pragma unroll
    for (int c = 0; c < 4; ++c) {
      uint4 v;
      int ob = (half * 32 + c * 8);
      v.x = (unsigned)f2b(sT[(ob + 0) * 132 + px]) | ((unsigned)f2b(sT[(ob + 1) * 132 + px]) << 16);
      v.y = (unsigned)f2b(sT[(ob + 2) * 132 + px]) | ((unsigned)f2b(sT[(ob + 3) * 132 + px]) << 16);
      v.z = (unsigned)f2b(sT[(ob + 4) * 132 + px]) | ((unsigned)f2b(sT[(ob + 5) * 132 + px]) << 16);
      v.w = (unsigned)f2b(sT[(ob + 6) * 132 + px]) | ((unsigned)f2b(sT[(ob + 7) * 132 + px]) << 16);
      *(uint4*)(op + c * 8) = v;
    }
    return;
  }
  b -= 512;
  {
    int r = b & 63;
    int n = b >> 6;
#pragma unroll
    for (int i = 0; i < 8; ++i) {
      int q = tid + i * 256;
      int ch = q >> 4, col4 = q & 15;
      float4 v = *(const float4*)(xd + ((size_t)(n * 128 + ch) * 64 + r) * 64 + col4 * 4);
      *(float4*)&sT[ch * 66 + col4 * 4] = v;
    }
    __syncthreads();
#pragma unroll
    for (int i = 0; i < 4; ++i) {
      int q = tid + i * 256;
      int col = q >> 4, cho = q & 15;
      uint4 v;
      int cb = cho * 8;
      v.x = (unsigned)f2b(sT[(cb + 0) * 66 + col]) | ((unsigned)f2b(sT[(cb + 1) * 66 + col]) << 16);
      v.y = (unsigned)f2b(sT[(cb + 2) * 66 + col]) | ((unsigned)f2b(sT[(cb + 3) * 66 + col]) << 16);
      v.z = (unsigned)f2b(sT[(cb + 4) * 66 + col]) | ((unsigned)f2b(sT[(cb + 5) * 66 + col]) << 16);
      v.w = (unsigned)f2b(sT[(cb + 6) * 66 + col]) | ((unsigned)f2b(sT[(cb + 7) * 66 + col]) << 16);
      *(uint4*)(xdh + (((size_t)(n * 64 + r)) * 64 + col) * 128 + cb) = v;
    }
  }
}

// ---------------------------------------------------------------------------
// Upsample + 2x2 conv (unchanged — validated)
// ---------------------------------------------------------------------------
__global__ __launch_bounds__(1024) void upconv_mf(
    const u16* __restrict__ xdh, const u16* __restrict__ wup,
    const float* __restrict__ bias, u16* __restrict__ outH) {
  __shared__ float s_red[4][3][16][64];
  const int tid = threadIdx.x;
  const int lane = tid & 63;
  const int w = tid >> 6;
  const int p2 = w >> 2;
  const int t = w & 3;
  const int y = blockIdx.x;
  const int n = blockIdx.y;
  const int px = (p2 << 5) + (lane & 31);
  const int h = lane >> 5;

  f32x16 acc0, acc1;
#pragma unroll
  for (int i = 0; i < 16; ++i) { acc0[i] = 0.f; acc1[i] = 0.f; }

  const u16* xb = xdh + ((size_t)n * 64 * 64) * 128;
  const int ty = t >> 1, tx = t & 1;
  const int row = min((y + ty) >> 1, 63);
  const int col = min((px + tx) >> 1, 63);
  const u16* src = xb + ((size_t)(row * 64 + col)) * 128;
#pragma unroll
  for (int ks = 0; ks < 8; ++ks) {
    U16B bf;
    bf.u = *(const uint4*)(src + ks * 16 + h * 8);
    const u16* wp = wup + ((size_t)((t * 8 + ks) * 2)) * 512 + lane * 8;
    U16B a0, a1;
    a0.u = *(const uint4*)wp;
    a1.u = *(const uint4*)(wp + 512);
    acc0 = __builtin_amdgcn_mfma_f32_32x32x16_bf16(a0.v, bf.v, acc0, 0, 0, 0);
    acc1 = __builtin_amdgcn_mfma_f32_32x32x16_bf16(a1.v, bf.v, acc1, 0, 0, 0);
  }

  const bool zero = (y == 127) || (px == 127);
  const size_t pixb = (((size_t)(n * 128 + y)) * 128 + px) * 64;

  if (t != 0) {
#pragma unroll
    for (int i = 0; i < 16; ++i) s_red[p2][t - 1][i][lane] = acc0[i];
  }
  __syncthreads();
  if (t == 0) {
#pragma unroll
    for (int q = 0; q < 4; ++q) {
      int oo = 8 * q + 4 * h;
      float v[4];
#pragma unroll
      for (int r = 0; r < 4; ++r) {
        int i = q * 4 + r;
        float s = acc0[i] + s_red[p2][0][i][lane] + s_red[p2][1][i][lane] +
                  s_red[p2][2][i][lane];
        v[r] = zero ? 0.f : (s + bias[oo + r]);
      }
      ushort4 hh;
      hh.x = f2b(v[0]); hh.y = f2b(v[1]); hh.z = f2b(v[2]); hh.w = f2b(v[3]);
      *(ushort4*)(outH + pixb + oo) = hh;
    }
  }
  __syncthreads();
  if (t != 0) {
#pragma unroll
    for (int i = 0; i < 16; ++i) s_red[p2][t - 1][i][lane] = acc1[i];
  }
  __syncthreads();
  if (t == 0) {
#pragma unroll
    for (int q = 0; q < 4; ++q) {
      int oo = 32 + 8 * q + 4 * h;
      float v[4];
#pragma unroll
      for (int r = 0; r < 4; ++r) {
        int i = q * 4 + r;
        float s = acc1[i] + s_red[p2][0][i][lane] + s_red[p2][1][i][lane] +
                  s_red[p2][2][i][lane];
        v[r] = zero ? 0.f : (s + bias[oo + r]);
      }
      ushort4 hh;
      hh.x = f2b(v[0]); hh.y = f2b(v[1]); hh.z = f2b(v[2]); hh.w = f2b(v[3]);
      *(ushort4*)(outH + pixb + oo) = hh;
    }
  }
}

// ---------------------------------------------------------------------------
// MFMA 3x3 conv with FULL-LINE staged loads (unchanged — validated).
// Used only for the Cin=192 cv conv now.
// ---------------------------------------------------------------------------
template <int NSEG>
__global__ __launch_bounds__(1024) void mfconv_s(
    const u16* __restrict__ in0, const u16* __restrict__ in1,
    const u16* __restrict__ in2, const u16* __restrict__ wpk,
    const float* __restrict__ bias, const u16* __restrict__ resh,
    float* __restrict__ outF, u16* __restrict__ outH, int mode) {
  __shared__ __align__(16) unsigned char s_un[49920];
  u16* stg = (u16*)s_un;
  float* s_redf = (float*)s_un;

  const int tid = threadIdx.x;
  const int lane = tid & 63;
  const int w = tid >> 6;
  const int p2 = w >> 2;
  const int kq = w & 3;
  const int y = blockIdx.x;
  const int n = blockIdx.y;
  const int px = (p2 << 5) + (lane & 31);
  const int h = lane >> 5;
  const int gpx = lane >> 3;
  const int gcs = lane & 7;

  auto stg_at = [&](int e, int cg, int p) -> u16* {
    return stg + (((e * 8 + cg) * 130 + p) << 3);
  };

  f32x16 acc0, acc1;
#pragma unroll
  for (int i = 0; i < 16; ++i) { acc0[i] = 0.f; acc1[i] = 0.f; }

  for (int s = 0; s < NSEG; ++s) {
    const u16* sp = (s == 0) ? in0 : ((s == 1) ? in1 : in2);
    const u16* bn = sp + ((size_t)n * 128) * 128 * 64;
    for (int i = w; i < 48; i += 16) {
      int ky = i >> 4, g = i & 15;
      int row = y + ky - 1;
      int ppx = g * 8 + gpx;
      uint4 v = make_uint4(0, 0, 0, 0);
      if ((unsigned)row < 128u)
        v = *(const uint4*)(bn + (size_t)row * (128 * 64) + (size_t)ppx * 64 + gcs * 8);
      *(uint4*)stg_at(ky, gcs, ppx) = v;
    }
    __syncthreads();
#pragma unroll
    for (int ky = 0; ky < 3; ++ky) {
#pragma unroll
      for (int kx = 0; kx < 3; ++kx) {
        int pxc = px + kx - 1;
        bool valid = (unsigned)pxc < 128u;
        int pxcc = min(max(pxc, 0), 127);
        U16B bf;
        bf.u = *(const uint4*)stg_at(ky, kq * 2 + h, pxcc);
        if (!valid) bf.u = make_uint4(0, 0, 0, 0);
        const u16* wp = wpk +
            ((size_t)((((s * 3 + ky) * 3 + kx) * 4 + kq) * 2)) * 512 + lane * 8;
        U16B a0, a1;
        a0.u = *(const uint4*)wp;
        a1.u = *(const uint4*)(wp + 512);
        acc0 = __builtin_amdgcn_mfma_f32_32x32x16_bf16(a0.v, bf.v, acc0, 0, 0, 0);
        acc1 = __builtin_amdgcn_mfma_f32_32x32x16_bf16(a1.v, bf.v, acc1, 0, 0, 0);
      }
    }
    __syncthreads();
  }

  const size_t pixb = ((size_t)(n * 128 + y)) * 128 + px;

  if (kq != 0) {
#pragma unroll
    for (int i = 0; i < 16; ++i)
      s_redf[((p2 * 3 + (kq - 1)) * 16 + i) * 64 + lane] = acc0[i];
  }
  __syncthreads();
  if (kq == 0) {
#pragma unroll
    for (int q = 0; q < 4; ++q) {
      int oo = 8 * q + 4 * h;
      float v[4];
#pragma unroll
      for (int r = 0; r < 4; ++r) {
        int i = q * 4 + r;
        v[r] = acc0[i] + s_redf[((p2 * 3 + 0) * 16 + i) * 64 + lane] +
               s_redf[((p2 * 3 + 1) * 16 + i) * 64 + lane] +
               s_redf[((p2 * 3 + 2) * 16 + i) * 64 + lane] + bias[oo + r];
      }
      if (mode == 1) {
#pragma unroll
        for (int r = 0; r < 4; ++r) v[r] = fmaxf(v[r], 0.f);
      } else if (mode == 3) {
        ushort4 rv = *(const ushort4*)(resh + pixb * 64 + oo);
        v[0] += b2f(rv.x); v[1] += b2f(rv.y); v[2] += b2f(rv.z); v[3] += b2f(rv.w);
      }
      if (outH) {
        ushort4 hh;
        hh.x = f2b(v[0]); hh.y = f2b(v[1]); hh.z = f2b(v[2]); hh.w = f2b(v[3]);
        *(ushort4*)(outH + pixb * 64 + oo) = hh;
      } else {
#pragma unroll
        for (int r = 0; r < 4; ++r)
          outF[((size_t)(n * 64 + oo + r)) * HW + y * 128 + px] = v[r];
      }
    }
  }
  __syncthreads();
  if (kq != 0) {
#pragma unroll
    for (int i = 0; i < 16; ++i)
      s_redf[((p2 * 3 + (kq - 1)) * 16 + i) * 64 + lane] = acc1[i];
  }
  __syncthreads();
  if (kq == 0) {
#pragma unroll
    for (int q = 0; q < 4; ++q) {
      int oo = 32 + 8 * q + 4 * h;
      float v[4];
#pragma unroll
      for (int r = 0; r < 4; ++r) {
        int i = q * 4 + r;
        v[r] = acc1[i] + s_redf[((p2 * 3 + 0) * 16 + i) * 64 + lane] +
               s_redf[((p2 * 3 + 1) * 16 + i) * 64 + lane] +
               s_redf[((p2 * 3 + 2) * 16 + i) * 64 + lane] + bias[oo + r];
      }
      if (mode == 1) {
#pragma unroll
        for (int r = 0; r < 4; ++r) v[r] = fmaxf(v[r], 0.f);
      } else if (mode == 3) {
        ushort4 rv = *(const ushort4*)(resh + pixb * 64 + oo);
        v[0] += b2f(rv.x); v[1] += b2f(rv.y); v[2] += b2f(rv.z); v[3] += b2f(rv.w);
      }
      if (outH) {
        ushort4 hh;
        hh.x = f2b(v[0]); hh.y = f2b(v[1]); hh.z = f2b(v[2]); hh.w = f2b(v[3]);
        *(ushort4*)(outH + pixb * 64 + oo) = hh;
      } else {
#pragma unroll
        for (int r = 0; r < 4; ++r)
          outF[((size_t)(n * 64 + oo + r)) * HW + y * 128 + px] = v[r];
      }
    }
  }
}

// ---------------------------------------------------------------------------
// Fused residual block: out = in + conv2(relu(conv1(in)+b1))+b2.
// Block = one row (y), 512 thr = 8 waves = 4 px-tiles x 2 och-halves.
// Each wave FULL-K (no cross-wave reduction). Ring of 3 staged input rows;
// conv1 computed for rows y-1..y+1 into bf16 mid (LDS); conv2 on row y.
// LDS = 96 KiB static. outH: bf16 NHWC; outF: fp32 NCHW (final).
// ---------------------------------------------------------------------------
__global__ __launch_bounds__(512) void rbfuse(
    const u16* __restrict__ in, const u16* __restrict__ w1,
    const float* __restrict__ b1, const u16* __restrict__ w2,
    const float* __restrict__ b2, float* __restrict__ outF,
    u16* __restrict__ outH) {
  __shared__ __align__(16) u16 ring[3][8][128][8];  // 48 KiB
  __shared__ __align__(16) u16 mid[3][8][128][8];   // 48 KiB
  const int tid = threadIdx.x;
  const int lane = tid & 63;
  const int w = tid >> 6;    // 8 waves
  const int p2 = w >> 1;     // px tile
  const int ot = w & 1;      // och half
  const int y = blockIdx.x;
  const int n = blockIdx.y;
  const int px = (p2 << 5) + (lane & 31);
  const int h = lane >> 5;
  const int gpx = lane >> 3;
  const int gcs = lane & 7;
  const u16* bn = in + ((size_t)n * 128) * 128 * 64;

  auto stage_row = [&](int r) {
    int sl = ((r % 3) + 3) % 3;
    for (int i = w; i < 16; i += 8) {
      int ppx = i * 8 + gpx;
      uint4 v = make_uint4(0, 0, 0, 0);
      if ((unsigned)r < 128u)
        v = *(const uint4*)(bn + (size_t)r * (128 * 64) + (size_t)ppx * 64 + gcs * 8);
      *(uint4*)&ring[sl][gcs][ppx][0] = v;
    }
  };

  auto conv1_row = [&](int rr, int r) {
    if ((unsigned)r >= 128u) {
      ushort4 z = make_ushort4(0, 0, 0, 0);
#pragma unroll
      for (int q = 0; q < 4; ++q)
        *(ushort4*)&mid[rr][ot * 4 + q][px][4 * h] = z;
      return;
    }
    f32x16 acc;
#pragma unroll
    for (int i = 0; i < 16; ++i) acc[i] = 0.f;
#pragma unroll
    for (int ky = 0; ky < 3; ++ky) {
      int sr = r - 1 + ky;
      int sl = ((sr % 3) + 3) % 3;
#pragma unroll
      for (int kx = 0; kx < 3; ++kx) {
        int pxc = px + kx - 1;
        bool valid = (unsigned)pxc < 128u;
        int pxcc = min(max(pxc, 0), 127);
#pragma unroll
        for (int kq = 0; kq < 4; ++kq) {
          U16B bf;
          bf.u = *(const uint4*)&ring[sl][kq * 2 + h][pxcc][0];
          if (!valid) bf.u = make_uint4(0, 0, 0, 0);
          U16B a;
          a.u = *(const uint4*)(w1 +
                ((size_t)(((ky * 3 + kx) * 4 + kq) * 2 + ot)) * 512 + lane * 8);
          acc = __builtin_amdgcn_mfma_f32_32x32x16_bf16(a.v, bf.v, acc, 0, 0, 0);
        }
      }
    }
#pragma unroll
    for (int q = 0; q < 4; ++q) {
      int oo = ot * 32 + 8 * q + 4 * h;
      ushort4 hh;
      hh.x = f2b(fmaxf(acc[q * 4 + 0] + b1[oo + 0], 0.f));
      hh.y = f2b(fmaxf(acc[q * 4 + 1] + b1[oo + 1], 0.f));
      hh.z = f2b(fmaxf(acc[q * 4 + 2] + b1[oo + 2], 0.f));
      hh.w = f2b(fmaxf(acc[q * 4 + 3] + b1[oo + 3], 0.f));
      *(ushort4*)&mid[rr][ot * 4 + q][px][4 * h] = hh;
    }
  };

  // sequence
  stage_row(y - 2);
  stage_row(y - 1);
  stage_row(y);
  __syncthreads();
  conv1_row(0, y - 1);
  __syncthreads();
  stage_row(y + 1);
  __syncthreads();
  conv1_row(1, y);
  __syncthreads();
  stage_row(y + 2);
  __syncthreads();
  conv1_row(2, y + 1);
  __syncthreads();

  // conv2 on row y + residual
  f32x16 acc;
#pragma unroll
  for (int i = 0; i < 16; ++i) acc[i] = 0.f;
#pragma unroll
  for (int ky = 0; ky < 3; ++ky) {
#pragma unroll
    for (int kx = 0; kx < 3; ++kx) {
      int pxc = px + kx - 1;
      bool valid = (unsigned)pxc < 128u;
      int pxcc = min(max(pxc, 0), 127);
#pragma unroll
      for (int kq = 0; kq < 4; ++kq) {
        U16B bf;
        bf.u = *(const uint4*)&mid[ky][kq * 2 + h][pxcc][0];
        if (!valid) bf.u = make_uint4(0, 0, 0, 0);
        U16B a;
        a.u = *(const uint4*)(w2 +
              ((size_t)(((ky * 3 + kx) * 4 + kq) * 2 + ot)) * 512 + lane * 8);
        acc = __builtin_amdgcn_mfma_f32_32x32x16_bf16(a.v, bf.v, acc, 0, 0, 0);
      }
    }
  }

  const int ysl = y % 3;  // ring still holds row y here
  const size_t pixb = ((size_t)(n * 128 + y)) * 128 + px;
#pragma unroll
  for (int q = 0; q < 4; ++q) {
    int oo = ot * 32 + 8 * q + 4 * h;
    ushort4 rv = *(const ushort4*)&ring[ysl][ot * 4 + q][px][4 * h];
    float v[4];
    v[0] = acc[q * 4 + 0] + b2[oo + 0] + b2f(rv.x);
    v[1] = acc[q * 4 + 1] + b2[oo + 1] + b2f(rv.y);
    v[2] = acc[q * 4 + 2] + b2[oo + 2] + b2f(rv.z);
    v[3] = acc[q * 4 + 3] + b2[oo + 3] + b2f(rv.w);
    if (outH) {
      ushort4 hh;
      hh.x = f2b(v[0]); hh.y = f2b(v[1]); hh.z = f2b(v[2]); hh.w = f2b(v[3]);
      *(ushort4*)(outH + pixb * 64 + oo) = hh;
    } else {
#pragma unroll
      for (int r = 0; r < 4; ++r)
        outF[((size_t)(n * 64 + oo + r)) * HW + y * 128 + px] = v[r];
    }
  }
}

// ---------------------------------------------------------------------------
// Fused offset-conv + deformable conv (unchanged — validated).
// ---------------------------------------------------------------------------
__global__ __launch_bounds__(1024) void deform_fused(
    const u16* __restrict__ in0, const u16* __restrict__ in1,
    const u16* __restrict__ in2, const u16* __restrict__ woff,
    const float* __restrict__ boff, const u16* __restrict__ xh,
    const u16* __restrict__ wdef, const float* __restrict__ bdef,
    u16* __restrict__ outH) {
  __shared__ float s_off[27][128];
  __shared__ __align__(16) unsigned char s_un[49920];
  u16* stg = (u16*)s_un;
  float* s_redf = (float*)s_un;

  const int tid = threadIdx.x;
  const int lane = tid & 63;
  const int w = tid >> 6;
  const int p2 = w >> 2;
  const int kq = w & 3;
  const int y = blockIdx.x;
  const int n = blockIdx.y;
  const int px = (p2 << 5) + (lane & 31);
  const int h = lane >> 5;
  const int gpx = lane >> 3;
  const int gcs = lane & 7;

  auto stg_at = [&](int e, int cg, int p) -> u16* {
    return stg + (((e * 8 + cg) * 130 + p) << 3);
  };

  // ================= Phase 1: offset conv =================
  f32x16 acc;
#pragma unroll
  for (int i = 0; i < 16; ++i) acc[i] = 0.f;

  for (int s = 0; s < 3; ++s) {
    const u16* sp = (s == 0) ? in0 : ((s == 1) ? in1 : in2);
    const u16* bn = sp + ((size_t)n * 128) * 128 * 64;
    for (int i = w; i < 48; i += 16) {
      int ky = i >> 4, g = i & 15;
      int row = y + ky - 1;
      int ppx = g * 8 + gpx;
      uint4 v = make_uint4(0, 0, 0, 0);
      if ((unsigned)row < 128u)
        v = *(const uint4*)(bn + (size_t)row * (128 * 64) + (size_t)ppx * 64 + gcs * 8);
      *(uint4*)stg_at(ky, gcs, ppx) = v;
    }
    __syncthreads();
#pragma unroll
    for (int ky = 0; ky < 3; ++ky) {
#pragma unroll
      for (int kx = 0; kx < 3; ++kx) {
        int pxc = px + kx - 1;
        bool valid = (unsigned)pxc < 128u;
        int pxcc = min(max(pxc, 0), 127);
        U16B bf;
        bf.u = *(const uint4*)stg_at(ky, kq * 2 + h, pxcc);
        if (!valid) bf.u = make_uint4(0, 0, 0, 0);
        U16B a;
        a.u = *(const uint4*)(woff +
              ((size_t)(((s * 3 + ky) * 3 + kx) * 4 + kq)) * 512 + lane * 8);
        acc = __builtin_amdgcn_mfma_f32_32x32x16_bf16(a.v, bf.v, acc, 0, 0, 0);
      }
    }
    __syncthreads();
  }

  if (kq != 0) {
#pragma unroll
    for (int i = 0; i < 16; ++i) s_redf[((p2 * 3 + (kq - 1)) * 16 + i) * 64 + lane] = acc[i];
  }
  __syncthreads();
  if (kq == 0) {
#pragma unroll
    for (int q = 0; q < 4; ++q) {
#pragma unroll
      for (int r = 0; r < 4; ++r) {
        int och = 8 * q + 4 * h + r;
        if (och < 27) {
          int i = q * 4 + r;
          float v = acc[i] + s_redf[((p2 * 3 + 0) * 16 + i) * 64 + lane] +
                    s_redf[((p2 * 3 + 1) * 16 + i) * 64 + lane] +
                    s_redf[((p2 * 3 + 2) * 16 + i) * 64 + lane] + boff[och];
          if (och >= 18) v = 1.f / (1.f + expf(-v));
          s_off[och][px] = v;
        }
      }
    }
  }
  __syncthreads();

  // ================= Phase 2: deform =================
  f32x16 acc0, acc1;
#pragma unroll
  for (int i = 0; i < 16; ++i) { acc0[i] = 0.f; acc1[i] = 0.f; }

  const u16* xb = xh + ((size_t)n * HW) * 64;

  for (int tc = 0; tc < 3; ++tc) {
    for (int i = w; i < 48; i += 16) {
      int tt = i >> 4, g = i & 15;
      int t = tc * 3 + tt;
      int ppx = g * 8 + gpx;
      int ky = t / 3 - 1, kx = t % 3 - 1;
      float dy = s_off[2 * t][ppx];
      float dx = s_off[2 * t + 1][ppx];
      float m = s_off[18 + t][ppx];
      float py = dy + (float)(y + ky);
      float pxf = dx + (float)(ppx + kx);
      float fy = floorf(py), fxx = floorf(pxf);
      float wy = py - fy, wx = pxf - fxx;
      int iy0 = (int)fy, ix0 = (int)fxx;
      bool vy0 = (unsigned)iy0 < 128u, vy1 = (unsigned)(iy0 + 1) < 128u;
      bool vx0 = (unsigned)ix0 < 128u, vx1 = (unsigned)(ix0 + 1) < 128u;
      float omwy = 1.f - wy, omwx = 1.f - wx;
      float f00 = (vy0 && vx0) ? omwy * omwx * m : 0.f;
      float f01 = (vy0 && vx1) ? omwy * wx * m : 0.f;
      float f10 = (vy1 && vx0) ? wy * omwx * m : 0.f;
      float f11 = (vy1 && vx1) ? wy * wx * m : 0.f;
      int y0c = min(max(iy0, 0), 127), y1c = min(max(iy0 + 1, 0), 127);
      int x0c = min(max(ix0, 0), 127), x1c = min(max(ix0 + 1, 0), 127);
      U16B v00, v01, v10, v11;
      v00.u = *(const uint4*)(xb + ((size_t)(y0c * 128 + x0c)) * 64 + gcs * 8);
      v01.u = *(const uint4*)(xb + ((size_t)(y0c * 128 + x1c)) * 64 + gcs * 8);
      v10.u = *(const uint4*)(xb + ((size_t)(y1c * 128 + x0c)) * 64 + gcs * 8);
      v11.u = *(const uint4*)(xb + ((size_t)(y1c * 128 + x1c)) * 64 + gcs * 8);
      unsigned dw[4];
#pragma unroll
      for (int jj = 0; jj < 4; ++jj) {
        float s0 = f00 * b2f(v00.s[2 * jj]) + f01 * b2f(v01.s[2 * jj]) +
                   f10 * b2f(v10.s[2 * jj]) + f11 * b2f(v11.s[2 * jj]);
        float s1 = f00 * b2f(v00.s[2 * jj + 1]) + f01 * b2f(v01.s[2 * jj + 1]) +
                   f10 * b2f(v10.s[2 * jj + 1]) + f11 * b2f(v11.s[2 * jj + 1]);
        dw[jj] = (unsigned)f2b(s0) | ((unsigned)f2b(s1) << 16);
      }
      *(uint4*)stg_at(tt, gcs, ppx) = make_uint4(dw[0], dw[1], dw[2], dw[3]);
    }
    __syncthreads();
#pragma unroll
    for (int tt = 0; tt < 3; ++tt) {
      int t = tc * 3 + tt;
      U16B bf;
      bf.u = *(const uint4*)stg_at(tt, kq * 2 + h, px);
      const u16* wp = wdef + ((size_t)((t * 4 + kq) * 2)) * 512 + lane * 8;
      U16B a0, a1;
      a0.u = *(const uint4*)wp;
      a1.u = *(const uint4*)(wp + 512);
      acc0 = __builtin_amdgcn_mfma_f32_32x32x16_bf16(a0.v, bf.v, acc0, 0, 0, 0);
      acc1 = __builtin_amdgcn_mfma_f32_32x32x16_bf16(a1.v, bf.v, acc1, 0, 0, 0);
    }
    __syncthreads();
  }

  const size_t pixb = (((size_t)(n * 128 + y)) * 128 + px) * 64;
  if (kq != 0) {
#pragma unroll
    for (int i = 0; i < 16; ++i) s_redf[((p2 * 3 + (kq - 1)) * 16 + i) * 64 + lane] = acc0[i];
  }
  __syncthreads();
  if (kq == 0) {
#pragma unroll
    for (int q = 0; q < 4; ++q) {
      int oo = 8 * q + 4 * h;
      float v[4];
#pragma unroll
      for (int r = 0; r < 4; ++r) {
        int i = q * 4 + r;
        v[r] = acc0[i] + s_redf[((p2 * 3 + 0) * 16 + i) * 64 + lane] +
               s_redf[((p2 * 3 + 1) * 16 + i) * 64 + lane] +
               s_redf[((p2 * 3 + 2) * 16 + i) * 64 + lane] + bdef[oo + r];
      }
      ushort4 hh;
      hh.x = f2b(v[0]); hh.y = f2b(v[1]); hh.z = f2b(v[2]); hh.w = f2b(v[3]);
      *(ushort4*)(outH + pixb + oo) = hh;
    }
  }
  __syncthreads();
  if (kq != 0) {
#pragma unroll
    for (int i = 0; i < 16; ++i) s_redf[((p2 * 3 + (kq - 1)) * 16 + i) * 64 + lane] = acc1[i];
  }
  __syncthreads();
  if (kq == 0) {
#pragma unroll
    for (int q = 0; q < 4; ++q) {
      int oo = 32 + 8 * q + 4 * h;
      float v[4];
#pragma unroll
      for (int r = 0; r < 4; ++r) {
        int i = q * 4 + r;
        v[r] = acc1[i] + s_redf[((p2 * 3 + 0) * 16 + i) * 64 + lane] +
               s_redf[((p2 * 3 + 1) * 16 + i) * 64 + lane] +
               s_redf[((p2 * 3 + 2) * 16 + i) * 64 + lane] + bdef[oo + r];
      }
      ushort4 hh;
      hh.x = f2b(v[0]); hh.y = f2b(v[1]); hh.z = f2b(v[2]); hh.w = f2b(v[3]);
      *(ushort4*)(outH + pixb + oo) = hh;
    }
  }
}

// ---------------------------------------------------------------------------
extern "C" void kernel_launch(void* const* d_in, const int* in_sizes, int n_in,
                              void* d_out, int out_size, void* d_ws, size_t ws_size,
                              hipStream_t stream) {
  const float* xd = (const float*)d_in[0];
  const float* xl = (const float*)d_in[1];
  const float* xr = (const float*)d_in[2];
  const float* up_w = (const float*)d_in[3];
  const float* up_b = (const float*)d_in[4];
  const float* offl_w = (const float*)d_in[5];
  const float* offl_b = (const float*)d_in[6];
  const float* dl_w = (const float*)d_in[7];
  const float* dl_b = (const float*)d_in[8];
  const float* offr_w = (const float*)d_in[9];
  const float* offr_b = (const float*)d_in[10];
  const float* dr_w = (const float*)d_in[11];
  const float* dr_b = (const float*)d_in[12];
  const float* cv_w = (const float*)d_in[13];
  const float* cv_b = (const float*)d_in[14];
  const float* rb1_w1 = (const float*)d_in[15];
  const float* rb1_w2 = (const float*)d_in[16];
  const float* rb2_w1 = (const float*)d_in[17];
  const float* rb2_w2 = (const float*)d_in[18];
  const float* rb1_b1 = (const float*)d_in[19];
  const float* rb1_b2 = (const float*)d_in[20];
  const float* rb2_b1 = (const float*)d_in[21];
  const float* rb2_b2 = (const float*)d_in[22];

  float* ws = (float*)d_ws;
  u16* hb = (u16*)(ws + 1769472);
  u16* xlh = hb;                   // 2097152 each
  u16* xrh = hb + 2097152;
  u16* xdph = hb + 4194304;
  u16* xl2h = hb + 6291456;
  u16* xr2h = hb + 8388608;
  u16* t0h = hb + 10485760;
  u16* t1h = hb + 12582912;
  u16* t2h = hb + 14680064;
  u16* t3h = hb + 16777216;
  u16* xdh = hb + 18874368;        // 1048576 (2*64*64*128)
  u16* wcv = hb + 19922944;        // 110592
  u16* wofl = hb + 20033536;       // 55296
  u16* wofr = hb + 20088832;       // 55296
  u16* wr1a = hb + 20144128;       // 36864
  u16* wr1b = hb + 20180992;
  u16* wr2a = hb + 20217856;
  u16* wr2b = hb + 20254720;
  u16* wdl = hb + 20291584;        // 36864
  u16* wdr = hb + 20328448;        // 36864
  u16* wup = hb + 20365312;        // 32768
  float* outp = (float*)d_out;

  hipLaunchKernelGGL(setup_kernel, dim3(2496), dim3(256), 0, stream,
                     dl_w, dr_w, up_w, cv_w, offl_w, offr_w, rb1_w1, rb1_w2,
                     rb2_w1, rb2_w2, wup, wdl, wdr, wcv, wofl, wofr, wr1a,
                     wr1b, wr2a, wr2b, xl, xr, xlh, xrh, xd, xdh);
  hipLaunchKernelGGL(upconv_mf, dim3(128, 2), dim3(1024), 0, stream,
                     xdh, wup, up_b, xdph);
  hipLaunchKernelGGL(deform_fused, dim3(128, 2), dim3(1024), 0, stream,
                     xlh, xrh, xdph, wofl, offl_b, xlh, wdl, dl_b, xl2h);
  hipLaunchKernelGGL(deform_fused, dim3(128, 2), dim3(1024), 0, stream,
                     xl2h, xrh, xdph, wofr, offr_b, xrh, wdr, dr_b, xr2h);
  hipLaunchKernelGGL(mfconv_s<3>, dim3(128, 2), dim3(1024), 0, stream,
                     xl2h, xr2h, xdph, wcv, cv_b, (const u16*)nullptr,
                     (float*)nullptr, t0h, 1);
  hipLaunchKernelGGL(rbfuse, dim3(128, 2), dim3(512), 0, stream,
                     t0h, wr1a, rb1_b1, wr1b, rb1_b2, (float*)nullptr, t2h);
  hipLaunchKernelGGL(rbfuse, dim3(128, 2), dim3(512), 0, stream,
                     t2h, wr2a, rb2_b1, wr2b, rb2_b2, outp, (u16*)nullptr);
}

// Round 16
// 131.536 us; speedup vs baseline: 1.4829x; 1.0065x over previous
//
#include <hip/hip_runtime.h>
#include <math.h>

#define HW 16384

typedef unsigned short u16;
typedef __attribute__((ext_vector_type(8))) short short8;
typedef __attribute__((ext_vector_type(16))) float f32x16;

union U16B {
  uint4 u;
  short8 v;
  u16 s[8];
};

__device__ inline u16 f2b(float f) {
  unsigned u = __float_as_uint(f);
  u += 0x7FFF + ((u >> 16) & 1);
  return (u16)(u >> 16);
}
__device__ inline float b2f(u16 h) {
  return __uint_as_float(((unsigned)h) << 16);
}

// ---------------------------------------------------------------------------
// Weight packing helpers (bf16 per-lane MFMA A-fragments).
// ---------------------------------------------------------------------------
__device__ inline u16 pack_frag(const float* __restrict__ w, int Cin, int O,
                                int OT, int d) {
  int j = d & 7;
  int lane = (d >> 3) & 63;
  int rest = d >> 9;
  int ot = rest % OT; rest /= OT;
  int ks = rest & 3; rest >>= 2;
  int kx = rest % 3; rest /= 3;
  int ky = rest % 3; int s = rest / 3;
  int och = ot * 32 + (lane & 31);
  int ch = s * 64 + ks * 16 + ((lane >> 5) << 3) + j;
  if (och >= O) return 0;
  return f2b(w[((size_t)och * Cin + ch) * 9 + ky * 3 + kx]);
}

__device__ inline u16 pack_def(const float* __restrict__ w, int d) {
  int j = d & 7;
  int lane = (d >> 3) & 63;
  int g = d >> 9;
  int ot = g & 1;
  int t = g >> 1;
  int ks = t & 3;
  int k = t >> 2;
  int och = ot * 32 + (lane & 31);
  int c = ks * 16 + ((lane >> 5) << 3) + j;
  return f2b(w[((size_t)och * 64 + c) * 9 + k]);
}

__device__ inline u16 pack_up(const float* __restrict__ w, int d) {
  int j = d & 7;
  int lane = (d >> 3) & 63;
  int g = d >> 9;
  int ot = g & 1;
  int rest = g >> 1;
  int ks = rest & 7;
  int t = rest >> 3;
  int och = ot * 32 + (lane & 31);
  int ci = ks * 16 + ((lane >> 5) << 3) + j;
  return f2b(w[((size_t)och * 128 + ci) * 4 + t]);
}

// ---------------------------------------------------------------------------
// setup_kernel (unchanged — validated)
// ---------------------------------------------------------------------------
__global__ __launch_bounds__(256) void setup_kernel(
    const float* __restrict__ dl_w, const float* __restrict__ dr_w,
    const float* __restrict__ up_w, const float* __restrict__ cv_w,
    const float* __restrict__ offl_w, const float* __restrict__ offr_w,
    const float* __restrict__ r1a, const float* __restrict__ r1b,
    const float* __restrict__ r2a, const float* __restrict__ r2b,
    u16* __restrict__ wup, u16* __restrict__ wdl, u16* __restrict__ wdr,
    u16* __restrict__ wcv, u16* __restrict__ wofl, u16* __restrict__ wofr,
    u16* __restrict__ wr1a, u16* __restrict__ wr1b,
    u16* __restrict__ wr2a, u16* __restrict__ wr2b,
    const float* __restrict__ xl, const float* __restrict__ xr,
    u16* __restrict__ xlh, u16* __restrict__ xrh,
    const float* __restrict__ xd, u16* __restrict__ xdh) {
  __shared__ float sT[8448];
  int tid = threadIdx.x;
  int b = blockIdx.x;
  if (b < 1856) {
    int d = b * 256 + tid;
    if (d < 32768) { wup[d] = pack_up(up_w, d); return; }
    d -= 32768;
    if (d < 36864) { wdl[d] = pack_def(dl_w, d); return; }
    d -= 36864;
    if (d < 36864) { wdr[d] = pack_def(dr_w, d); return; }
    d -= 36864;
    if (d < 110592) { wcv[d] = pack_frag(cv_w, 192, 64, 2, d); return; }
    d -= 110592;
    if (d < 55296) { wofl[d] = pack_frag(offl_w, 192, 27, 1, d); return; }
    d -= 55296;
    if (d < 55296) { wofr[d] = pack_frag(offr_w, 192, 27, 1, d); return; }
    d -= 55296;
    if (d < 36864) { wr1a[d] = pack_frag(r1a, 64, 64, 2, d); return; }
    d -= 36864;
    if (d < 36864) { wr1b[d] = pack_frag(r1b, 64, 64, 2, d); return; }
    d -= 36864;
    if (d < 36864) { wr2a[d] = pack_frag(r2a, 64, 64, 2, d); return; }
    d -= 36864;
    if (d < 36864) { wr2b[d] = pack_frag(r2b, 64, 64, 2, d); return; }
    return;
  }
  b -= 1856;
  if (b < 512) {
    int y = b & 127;
    int pid = b >> 7;
    const float* src = (pid >> 1) ? xr : xl;
    u16* dst = (pid >> 1) ? xrh : xlh;
    int n = pid & 1;
#pragma unroll
    for (int i = 0; i < 8; ++i) {
      int q = tid + i * 256;
      int ch = q >> 5, pxq = q & 31;
      float4 v = *(const float4*)(src + ((size_t)(n * 64 + ch)) * HW + y * 128 + pxq * 4);
      *(float4*)&sT[ch * 132 + pxq * 4] = v;
    }
    __syncthreads();
    int px = tid >> 1, half = tid & 1;
    u16* op = dst + (((size_t)(n * 128 + y)) * 128 + px) * 64 + half * 32;
#pragma unroll
    for (int c = 0; c < 4; ++c) {
      uint4 v;
      int ob = (half * 32 + c * 8);
      v.x = (unsigned)f2b(sT[(ob + 0) * 132 + px]) | ((unsigned)f2b(sT[(ob + 1) * 132 + px]) << 16);
      v.y = (unsigned)f2b(sT[(ob + 2) * 132 + px]) | ((unsigned)f2b(sT[(ob + 3) * 132 + px]) << 16);
      v.z = (unsigned)f2b(sT[(ob + 4) * 132 + px]) | ((unsigned)f2b(sT[(ob + 5) * 132 + px]) << 16);
      v.w = (unsigned)f2b(sT[(ob + 6) * 132 + px]) | ((unsigned)f2b(sT[(ob + 7) * 132 + px]) << 16);
      *(uint4*)(op + c * 8) = v;
    }
    return;
  }
  b -= 512;
  {
    int r = b & 63;
    int n = b >> 6;
#pragma unroll
    for (int i = 0; i < 8; ++i) {
      int q = tid + i * 256;
      int ch = q >> 4, col4 = q & 15;
      float4 v = *(const float4*)(xd + ((size_t)(n * 128 + ch) * 64 + r) * 64 + col4 * 4);
      *(float4*)&sT[ch * 66 + col4 * 4] = v;
    }
    __syncthreads();
#pragma unroll
    for (int i = 0; i < 4; ++i) {
      int q = tid + i * 256;
      int col = q >> 4, cho = q & 15;
      uint4 v;
      int cb = cho * 8;
      v.x = (unsigned)f2b(sT[(cb + 0) * 66 + col]) | ((unsigned)f2b(sT[(cb + 1) * 66 + col]) << 16);
      v.y = (unsigned)f2b(sT[(cb + 2) * 66 + col]) | ((unsigned)f2b(sT[(cb + 3) * 66 + col]) << 16);
      v.z = (unsigned)f2b(sT[(cb + 4) * 66 + col]) | ((unsigned)f2b(sT[(cb + 5) * 66 + col]) << 16);
      v.w = (unsigned)f2b(sT[(cb + 6) * 66 + col]) | ((unsigned)f2b(sT[(cb + 7) * 66 + col]) << 16);
      *(uint4*)(xdh + (((size_t)(n * 64 + r)) * 64 + col) * 128 + cb) = v;
    }
  }
}

// ---------------------------------------------------------------------------
// Upsample + 2x2 conv (unchanged — validated)
// ---------------------------------------------------------------------------
__global__ __launch_bounds__(1024) void upconv_mf(
    const u16* __restrict__ xdh, const u16* __restrict__ wup,
    const float* __restrict__ bias, u16* __restrict__ outH) {
  __shared__ float s_red[4][3][16][64];
  const int tid = threadIdx.x;
  const int lane = tid & 63;
  const int w = tid >> 6;
  const int p2 = w >> 2;
  const int t = w & 3;
  const int y = blockIdx.x;
  const int n = blockIdx.y;
  const int px = (p2 << 5) + (lane & 31);
  const int h = lane >> 5;

  f32x16 acc0, acc1;
#pragma unroll
  for (int i = 0; i < 16; ++i) { acc0[i] = 0.f; acc1[i] = 0.f; }

  const u16* xb = xdh + ((size_t)n * 64 * 64) * 128;
  const int ty = t >> 1, tx = t & 1;
  const int row = min((y + ty) >> 1, 63);
  const int col = min((px + tx) >> 1, 63);
  const u16* src = xb + ((size_t)(row * 64 + col)) * 128;
#pragma unroll
  for (int ks = 0; ks < 8; ++ks) {
    U16B bf;
    bf.u = *(const uint4*)(src + ks * 16 + h * 8);
    const u16* wp = wup + ((size_t)((t * 8 + ks) * 2)) * 512 + lane * 8;
    U16B a0, a1;
    a0.u = *(const uint4*)wp;
    a1.u = *(const uint4*)(wp + 512);
    acc0 = __builtin_amdgcn_mfma_f32_32x32x16_bf16(a0.v, bf.v, acc0, 0, 0, 0);
    acc1 = __builtin_amdgcn_mfma_f32_32x32x16_bf16(a1.v, bf.v, acc1, 0, 0, 0);
  }

  const bool zero = (y == 127) || (px == 127);
  const size_t pixb = (((size_t)(n * 128 + y)) * 128 + px) * 64;

  if (t != 0) {
#pragma unroll
    for (int i = 0; i < 16; ++i) s_red[p2][t - 1][i][lane] = acc0[i];
  }
  __syncthreads();
  if (t == 0) {
#pragma unroll
    for (int q = 0; q < 4; ++q) {
      int oo = 8 * q + 4 * h;
      float v[4];
#pragma unroll
      for (int r = 0; r < 4; ++r) {
        int i = q * 4 + r;
        float s = acc0[i] + s_red[p2][0][i][lane] + s_red[p2][1][i][lane] +
                  s_red[p2][2][i][lane];
        v[r] = zero ? 0.f : (s + bias[oo + r]);
      }
      ushort4 hh;
      hh.x = f2b(v[0]); hh.y = f2b(v[1]); hh.z = f2b(v[2]); hh.w = f2b(v[3]);
      *(ushort4*)(outH + pixb + oo) = hh;
    }
  }
  __syncthreads();
  if (t != 0) {
#pragma unroll
    for (int i = 0; i < 16; ++i) s_red[p2][t - 1][i][lane] = acc1[i];
  }
  __syncthreads();
  if (t == 0) {
#pragma unroll
    for (int q = 0; q < 4; ++q) {
      int oo = 32 + 8 * q + 4 * h;
      float v[4];
#pragma unroll
      for (int r = 0; r < 4; ++r) {
        int i = q * 4 + r;
        float s = acc1[i] + s_red[p2][0][i][lane] + s_red[p2][1][i][lane] +
                  s_red[p2][2][i][lane];
        v[r] = zero ? 0.f : (s + bias[oo + r]);
      }
      ushort4 hh;
      hh.x = f2b(v[0]); hh.y = f2b(v[1]); hh.z = f2b(v[2]); hh.w = f2b(v[3]);
      *(ushort4*)(outH + pixb + oo) = hh;
    }
  }
}

// ---------------------------------------------------------------------------
// MFMA 3x3 conv with FULL-LINE staged loads (unchanged — validated).
// ---------------------------------------------------------------------------
template <int NSEG>
__global__ __launch_bounds__(1024) void mfconv_s(
    const u16* __restrict__ in0, const u16* __restrict__ in1,
    const u16* __restrict__ in2, const u16* __restrict__ wpk,
    const float* __restrict__ bias, const u16* __restrict__ resh,
    float* __restrict__ outF, u16* __restrict__ outH, int mode) {
  __shared__ __align__(16) unsigned char s_un[49920];
  u16* stg = (u16*)s_un;
  float* s_redf = (float*)s_un;

  const int tid = threadIdx.x;
  const int lane = tid & 63;
  const int w = tid >> 6;
  const int p2 = w >> 2;
  const int kq = w & 3;
  const int y = blockIdx.x;
  const int n = blockIdx.y;
  const int px = (p2 << 5) + (lane & 31);
  const int h = lane >> 5;
  const int gpx = lane >> 3;
  const int gcs = lane & 7;

  auto stg_at = [&](int e, int cg, int p) -> u16* {
    return stg + (((e * 8 + cg) * 130 + p) << 3);
  };

  f32x16 acc0, acc1;
#pragma unroll
  for (int i = 0; i < 16; ++i) { acc0[i] = 0.f; acc1[i] = 0.f; }

  for (int s = 0; s < NSEG; ++s) {
    const u16* sp = (s == 0) ? in0 : ((s == 1) ? in1 : in2);
    const u16* bn = sp + ((size_t)n * 128) * 128 * 64;
    for (int i = w; i < 48; i += 16) {
      int ky = i >> 4, g = i & 15;
      int row = y + ky - 1;
      int ppx = g * 8 + gpx;
      uint4 v = make_uint4(0, 0, 0, 0);
      if ((unsigned)row < 128u)
        v = *(const uint4*)(bn + (size_t)row * (128 * 64) + (size_t)ppx * 64 + gcs * 8);
      *(uint4*)stg_at(ky, gcs, ppx) = v;
    }
    __syncthreads();
#pragma unroll
    for (int ky = 0; ky < 3; ++ky) {
#pragma unroll
      for (int kx = 0; kx < 3; ++kx) {
        int pxc = px + kx - 1;
        bool valid = (unsigned)pxc < 128u;
        int pxcc = min(max(pxc, 0), 127);
        U16B bf;
        bf.u = *(const uint4*)stg_at(ky, kq * 2 + h, pxcc);
        if (!valid) bf.u = make_uint4(0, 0, 0, 0);
        const u16* wp = wpk +
            ((size_t)((((s * 3 + ky) * 3 + kx) * 4 + kq) * 2)) * 512 + lane * 8;
        U16B a0, a1;
        a0.u = *(const uint4*)wp;
        a1.u = *(const uint4*)(wp + 512);
        acc0 = __builtin_amdgcn_mfma_f32_32x32x16_bf16(a0.v, bf.v, acc0, 0, 0, 0);
        acc1 = __builtin_amdgcn_mfma_f32_32x32x16_bf16(a1.v, bf.v, acc1, 0, 0, 0);
      }
    }
    __syncthreads();
  }

  const size_t pixb = ((size_t)(n * 128 + y)) * 128 + px;

  if (kq != 0) {
#pragma unroll
    for (int i = 0; i < 16; ++i)
      s_redf[((p2 * 3 + (kq - 1)) * 16 + i) * 64 + lane] = acc0[i];
  }
  __syncthreads();
  if (kq == 0) {
#pragma unroll
    for (int q = 0; q < 4; ++q) {
      int oo = 8 * q + 4 * h;
      float v[4];
#pragma unroll
      for (int r = 0; r < 4; ++r) {
        int i = q * 4 + r;
        v[r] = acc0[i] + s_redf[((p2 * 3 + 0) * 16 + i) * 64 + lane] +
               s_redf[((p2 * 3 + 1) * 16 + i) * 64 + lane] +
               s_redf[((p2 * 3 + 2) * 16 + i) * 64 + lane] + bias[oo + r];
      }
      if (mode == 1) {
#pragma unroll
        for (int r = 0; r < 4; ++r) v[r] = fmaxf(v[r], 0.f);
      } else if (mode == 3) {
        ushort4 rv = *(const ushort4*)(resh + pixb * 64 + oo);
        v[0] += b2f(rv.x); v[1] += b2f(rv.y); v[2] += b2f(rv.z); v[3] += b2f(rv.w);
      }
      if (outH) {
        ushort4 hh;
        hh.x = f2b(v[0]); hh.y = f2b(v[1]); hh.z = f2b(v[2]); hh.w = f2b(v[3]);
        *(ushort4*)(outH + pixb * 64 + oo) = hh;
      } else {
#pragma unroll
        for (int r = 0; r < 4; ++r)
          outF[((size_t)(n * 64 + oo + r)) * HW + y * 128 + px] = v[r];
      }
    }
  }
  __syncthreads();
  if (kq != 0) {
#pragma unroll
    for (int i = 0; i < 16; ++i)
      s_redf[((p2 * 3 + (kq - 1)) * 16 + i) * 64 + lane] = acc1[i];
  }
  __syncthreads();
  if (kq == 0) {
#pragma unroll
    for (int q = 0; q < 4; ++q) {
      int oo = 32 + 8 * q + 4 * h;
      float v[4];
#pragma unroll
      for (int r = 0; r < 4; ++r) {
        int i = q * 4 + r;
        v[r] = acc1[i] + s_redf[((p2 * 3 + 0) * 16 + i) * 64 + lane] +
               s_redf[((p2 * 3 + 1) * 16 + i) * 64 + lane] +
               s_redf[((p2 * 3 + 2) * 16 + i) * 64 + lane] + bias[oo + r];
      }
      if (mode == 1) {
#pragma unroll
        for (int r = 0; r < 4; ++r) v[r] = fmaxf(v[r], 0.f);
      } else if (mode == 3) {
        ushort4 rv = *(const ushort4*)(resh + pixb * 64 + oo);
        v[0] += b2f(rv.x); v[1] += b2f(rv.y); v[2] += b2f(rv.z); v[3] += b2f(rv.w);
      }
      if (outH) {
        ushort4 hh;
        hh.x = f2b(v[0]); hh.y = f2b(v[1]); hh.z = f2b(v[2]); hh.w = f2b(v[3]);
        *(ushort4*)(outH + pixb * 64 + oo) = hh;
      } else {
#pragma unroll
        for (int r = 0; r < 4; ++r)
          outF[((size_t)(n * 64 + oo + r)) * HW + y * 128 + px] = v[r];
      }
    }
  }
}

// ---------------------------------------------------------------------------
// Fused residual block (unchanged — validated)
// ---------------------------------------------------------------------------
__global__ __launch_bounds__(512) void rbfuse(
    const u16* __restrict__ in, const u16* __restrict__ w1,
    const float* __restrict__ b1, const u16* __restrict__ w2,
    const float* __restrict__ b2, float* __restrict__ outF,
    u16* __restrict__ outH) {
  __shared__ __align__(16) u16 ring[3][8][128][8];
  __shared__ __align__(16) u16 mid[3][8][128][8];
  const int tid = threadIdx.x;
  const int lane = tid & 63;
  const int w = tid >> 6;
  const int p2 = w >> 1;
  const int ot = w & 1;
  const int y = blockIdx.x;
  const int n = blockIdx.y;
  const int px = (p2 << 5) + (lane & 31);
  const int h = lane >> 5;
  const int gpx = lane >> 3;
  const int gcs = lane & 7;
  const u16* bn = in + ((size_t)n * 128) * 128 * 64;

  auto stage_row = [&](int r) {
    int sl = ((r % 3) + 3) % 3;
    for (int i = w; i < 16; i += 8) {
      int ppx = i * 8 + gpx;
      uint4 v = make_uint4(0, 0, 0, 0);
      if ((unsigned)r < 128u)
        v = *(const uint4*)(bn + (size_t)r * (128 * 64) + (size_t)ppx * 64 + gcs * 8);
      *(uint4*)&ring[sl][gcs][ppx][0] = v;
    }
  };

  auto conv1_row = [&](int rr, int r) {
    if ((unsigned)r >= 128u) {
      ushort4 z = make_ushort4(0, 0, 0, 0);
#pragma unroll
      for (int q = 0; q < 4; ++q)
        *(ushort4*)&mid[rr][ot * 4 + q][px][4 * h] = z;
      return;
    }
    f32x16 acc;
#pragma unroll
    for (int i = 0; i < 16; ++i) acc[i] = 0.f;
#pragma unroll
    for (int ky = 0; ky < 3; ++ky) {
      int sr = r - 1 + ky;
      int sl = ((sr % 3) + 3) % 3;
#pragma unroll
      for (int kx = 0; kx < 3; ++kx) {
        int pxc = px + kx - 1;
        bool valid = (unsigned)pxc < 128u;
        int pxcc = min(max(pxc, 0), 127);
#pragma unroll
        for (int kq = 0; kq < 4; ++kq) {
          U16B bf;
          bf.u = *(const uint4*)&ring[sl][kq * 2 + h][pxcc][0];
          if (!valid) bf.u = make_uint4(0, 0, 0, 0);
          U16B a;
          a.u = *(const uint4*)(w1 +
                ((size_t)(((ky * 3 + kx) * 4 + kq) * 2 + ot)) * 512 + lane * 8);
          acc = __builtin_amdgcn_mfma_f32_32x32x16_bf16(a.v, bf.v, acc, 0, 0, 0);
        }
      }
    }
#pragma unroll
    for (int q = 0; q < 4; ++q) {
      int oo = ot * 32 + 8 * q + 4 * h;
      ushort4 hh;
      hh.x = f2b(fmaxf(acc[q * 4 + 0] + b1[oo + 0], 0.f));
      hh.y = f2b(fmaxf(acc[q * 4 + 1] + b1[oo + 1], 0.f));
      hh.z = f2b(fmaxf(acc[q * 4 + 2] + b1[oo + 2], 0.f));
      hh.w = f2b(fmaxf(acc[q * 4 + 3] + b1[oo + 3], 0.f));
      *(ushort4*)&mid[rr][ot * 4 + q][px][4 * h] = hh;
    }
  };

  stage_row(y - 2);
  stage_row(y - 1);
  stage_row(y);
  __syncthreads();
  conv1_row(0, y - 1);
  __syncthreads();
  stage_row(y + 1);
  __syncthreads();
  conv1_row(1, y);
  __syncthreads();
  stage_row(y + 2);
  __syncthreads();
  conv1_row(2, y + 1);
  __syncthreads();

  f32x16 acc;
#pragma unroll
  for (int i = 0; i < 16; ++i) acc[i] = 0.f;
#pragma unroll
  for (int ky = 0; ky < 3; ++ky) {
#pragma unroll
    for (int kx = 0; kx < 3; ++kx) {
      int pxc = px + kx - 1;
      bool valid = (unsigned)pxc < 128u;
      int pxcc = min(max(pxc, 0), 127);
#pragma unroll
      for (int kq = 0; kq < 4; ++kq) {
        U16B bf;
        bf.u = *(const uint4*)&mid[ky][kq * 2 + h][pxcc][0];
        if (!valid) bf.u = make_uint4(0, 0, 0, 0);
        U16B a;
        a.u = *(const uint4*)(w2 +
              ((size_t)(((ky * 3 + kx) * 4 + kq) * 2 + ot)) * 512 + lane * 8);
        acc = __builtin_amdgcn_mfma_f32_32x32x16_bf16(a.v, bf.v, acc, 0, 0, 0);
      }
    }
  }

  const int ysl = y % 3;
  const size_t pixb = ((size_t)(n * 128 + y)) * 128 + px;
#pragma unroll
  for (int q = 0; q < 4; ++q) {
    int oo = ot * 32 + 8 * q + 4 * h;
    ushort4 rv = *(const ushort4*)&ring[ysl][ot * 4 + q][px][4 * h];
    float v[4];
    v[0] = acc[q * 4 + 0] + b2[oo + 0] + b2f(rv.x);
    v[1] = acc[q * 4 + 1] + b2[oo + 1] + b2f(rv.y);
    v[2] = acc[q * 4 + 2] + b2[oo + 2] + b2f(rv.z);
    v[3] = acc[q * 4 + 3] + b2[oo + 3] + b2f(rv.w);
    if (outH) {
      ushort4 hh;
      hh.x = f2b(v[0]); hh.y = f2b(v[1]); hh.z = f2b(v[2]); hh.w = f2b(v[3]);
      *(ushort4*)(outH + pixb * 64 + oo) = hh;
    } else {
#pragma unroll
      for (int r = 0; r < 4; ++r)
        outF[((size_t)(n * 64 + oo + r)) * HW + y * 128 + px] = v[r];
    }
  }
}

// ---------------------------------------------------------------------------
// Fused offset-conv + deformable conv, HALF-ROW blocks for 2 blocks/CU.
// Block = 64 px, 512 thr = 8 waves = 2 px-tiles x 4 ks/tap-quarters.
// grid = (128 rows * 2 halves, n) = 512 blocks. LDS 37.6 KB (s_off[27][64]
// + 30.7KB union: stg[3][8][80][8] with px halo staged-as-zero / s_red).
// Phase structure identical to the validated R12 version.
// ---------------------------------------------------------------------------
__global__ __launch_bounds__(512) void deform_fused(
    const u16* __restrict__ in0, const u16* __restrict__ in1,
    const u16* __restrict__ in2, const u16* __restrict__ woff,
    const float* __restrict__ boff, const u16* __restrict__ xh,
    const u16* __restrict__ wdef, const float* __restrict__ bdef,
    u16* __restrict__ outH) {
  __shared__ float s_off[27][64];
  __shared__ __align__(16) unsigned char s_un[30720];
  u16* stg = (u16*)s_un;            // [e<3][cg<8][80][8ch] (phase1: px halo)
  float* s_redf = (float*)s_un;     // [p2<2][3][16][64]

  const int tid = threadIdx.x;
  const int lane = tid & 63;
  const int w = tid >> 6;    // 8 waves
  const int p2 = w >> 2;     // px tile (0..1)
  const int kq = w & 3;      // quarter
  const int y = blockIdx.x >> 1;
  const int hx0 = (blockIdx.x & 1) << 6;
  const int n = blockIdx.y;
  const int lp = (p2 << 5) + (lane & 31);  // local px 0..63
  const int h = lane >> 5;
  const int gpx = lane >> 3;
  const int gcs = lane & 7;

  auto stg_at = [&](int e, int cg, int p) -> u16* {
    return stg + (((e * 8 + cg) * 80 + p) << 3);
  };

  // ================= Phase 1: offset conv =================
  f32x16 acc;
#pragma unroll
  for (int i = 0; i < 16; ++i) acc[i] = 0.f;

  for (int s = 0; s < 3; ++s) {
    const u16* sp = (s == 0) ? in0 : ((s == 1) ? in1 : in2);
    const u16* bn = sp + ((size_t)n * 128) * 128 * 64;
    // stage 3 rows x 80 px (halo incl.): 30 units (ky, g<10), <=4 per wave
    for (int i = w; i < 30; i += 8) {
      int ky = i / 10, g = i % 10;
      int row = y + ky - 1;
      int ppx = hx0 - 8 + g * 8 + gpx;  // global px
      uint4 v = make_uint4(0, 0, 0, 0);
      if ((unsigned)row < 128u && (unsigned)ppx < 128u)
        v = *(const uint4*)(bn + (size_t)row * (128 * 64) + (size_t)ppx * 64 + gcs * 8);
      *(uint4*)stg_at(ky, gcs, g * 8 + gpx) = v;
    }
    __syncthreads();
#pragma unroll
    for (int ky = 0; ky < 3; ++ky) {
#pragma unroll
      for (int kx = 0; kx < 3; ++kx) {
        U16B bf;
        bf.u = *(const uint4*)stg_at(ky, kq * 2 + h, lp + 7 + kx);
        U16B a;
        a.u = *(const uint4*)(woff +
              ((size_t)(((s * 3 + ky) * 3 + kx) * 4 + kq)) * 512 + lane * 8);
        acc = __builtin_amdgcn_mfma_f32_32x32x16_bf16(a.v, bf.v, acc, 0, 0, 0);
      }
    }
    __syncthreads();
  }

  if (kq != 0) {
#pragma unroll
    for (int i = 0; i < 16; ++i)
      s_redf[((p2 * 3 + (kq - 1)) * 16 + i) * 64 + lane] = acc[i];
  }
  __syncthreads();
  if (kq == 0) {
#pragma unroll
    for (int q = 0; q < 4; ++q) {
#pragma unroll
      for (int r = 0; r < 4; ++r) {
        int och = 8 * q + 4 * h + r;
        if (och < 27) {
          int i = q * 4 + r;
          float v = acc[i] + s_redf[((p2 * 3 + 0) * 16 + i) * 64 + lane] +
                    s_redf[((p2 * 3 + 1) * 16 + i) * 64 + lane] +
                    s_redf[((p2 * 3 + 2) * 16 + i) * 64 + lane] + boff[och];
          if (och >= 18) v = 1.f / (1.f + expf(-v));
          s_off[och][lp] = v;
        }
      }
    }
  }
  __syncthreads();

  // ================= Phase 2: deform =================
  f32x16 acc0, acc1;
#pragma unroll
  for (int i = 0; i < 16; ++i) { acc0[i] = 0.f; acc1[i] = 0.f; }

  const u16* xb = xh + ((size_t)n * HW) * 64;

  for (int tc = 0; tc < 3; ++tc) {
    // gather-blend chunk: 24 units (tt<3, g<8), 3 per wave
    for (int i = w; i < 24; i += 8) {
      int tt = i >> 3, g = i & 7;
      int t = tc * 3 + tt;
      int ppx = g * 8 + gpx;          // local px
      int gx = hx0 + ppx;             // global px
      int ky = t / 3 - 1, kx = t % 3 - 1;
      float dy = s_off[2 * t][ppx];
      float dx = s_off[2 * t + 1][ppx];
      float m = s_off[18 + t][ppx];
      float py = dy + (float)(y + ky);
      float pxf = dx + (float)(gx + kx);
      float fy = floorf(py), fxx = floorf(pxf);
      float wy = py - fy, wx = pxf - fxx;
      int iy0 = (int)fy, ix0 = (int)fxx;
      bool vy0 = (unsigned)iy0 < 128u, vy1 = (unsigned)(iy0 + 1) < 128u;
      bool vx0 = (unsigned)ix0 < 128u, vx1 = (unsigned)(ix0 + 1) < 128u;
      float omwy = 1.f - wy, omwx = 1.f - wx;
      float f00 = (vy0 && vx0) ? omwy * omwx * m : 0.f;
      float f01 = (vy0 && vx1) ? omwy * wx * m : 0.f;
      float f10 = (vy1 && vx0) ? wy * omwx * m : 0.f;
      float f11 = (vy1 && vx1) ? wy * wx * m : 0.f;
      int y0c = min(max(iy0, 0), 127), y1c = min(max(iy0 + 1, 0), 127);
      int x0c = min(max(ix0, 0), 127), x1c = min(max(ix0 + 1, 0), 127);
      U16B v00, v01, v10, v11;
      v00.u = *(const uint4*)(xb + ((size_t)(y0c * 128 + x0c)) * 64 + gcs * 8);
      v01.u = *(const uint4*)(xb + ((size_t)(y0c * 128 + x1c)) * 64 + gcs * 8);
      v10.u = *(const uint4*)(xb + ((size_t)(y1c * 128 + x0c)) * 64 + gcs * 8);
      v11.u = *(const uint4*)(xb + ((size_t)(y1c * 128 + x1c)) * 64 + gcs * 8);
      unsigned dw[4];
#pragma unroll
      for (int jj = 0; jj < 4; ++jj) {
        float s0 = f00 * b2f(v00.s[2 * jj]) + f01 * b2f(v01.s[2 * jj]) +
                   f10 * b2f(v10.s[2 * jj]) + f11 * b2f(v11.s[2 * jj]);
        float s1 = f00 * b2f(v00.s[2 * jj + 1]) + f01 * b2f(v01.s[2 * jj + 1]) +
                   f10 * b2f(v10.s[2 * jj + 1]) + f11 * b2f(v11.s[2 * jj + 1]);
        dw[jj] = (unsigned)f2b(s0) | ((unsigned)f2b(s1) << 16);
      }
      *(uint4*)stg_at(tt, gcs, ppx) = make_uint4(dw[0], dw[1], dw[2], dw[3]);
    }
    __syncthreads();
#pragma unroll
    for (int tt = 0; tt < 3; ++tt) {
      int t = tc * 3 + tt;
      U16B bf;
      bf.u = *(const uint4*)stg_at(tt, kq * 2 + h, lp);
      const u16* wp = wdef + ((size_t)((t * 4 + kq) * 2)) * 512 + lane * 8;
      U16B a0, a1;
      a0.u = *(const uint4*)wp;
      a1.u = *(const uint4*)(wp + 512);
      acc0 = __builtin_amdgcn_mfma_f32_32x32x16_bf16(a0.v, bf.v, acc0, 0, 0, 0);
      acc1 = __builtin_amdgcn_mfma_f32_32x32x16_bf16(a1.v, bf.v, acc1, 0, 0, 0);
    }
    __syncthreads();
  }

  // ================= reductions + store =================
  const size_t pixb = (((size_t)(n * 128 + y)) * 128 + hx0 + lp) * 64;
  if (kq != 0) {
#pragma unroll
    for (int i = 0; i < 16; ++i)
      s_redf[((p2 * 3 + (kq - 1)) * 16 + i) * 64 + lane] = acc0[i];
  }
  __syncthreads();
  if (kq == 0) {
#pragma unroll
    for (int q = 0; q < 4; ++q) {
      int oo = 8 * q + 4 * h;
      float v[4];
#pragma unroll
      for (int r = 0; r < 4; ++r) {
        int i = q * 4 + r;
        v[r] = acc0[i] + s_redf[((p2 * 3 + 0) * 16 + i) * 64 + lane] +
               s_redf[((p2 * 3 + 1) * 16 + i) * 64 + lane] +
               s_redf[((p2 * 3 + 2) * 16 + i) * 64 + lane] + bdef[oo + r];
      }
      ushort4 hh;
      hh.x = f2b(v[0]); hh.y = f2b(v[1]); hh.z = f2b(v[2]); hh.w = f2b(v[3]);
      *(ushort4*)(outH + pixb + oo) = hh;
    }
  }
  __syncthreads();
  if (kq != 0) {
#pragma unroll
    for (int i = 0; i < 16; ++i)
      s_redf[((p2 * 3 + (kq - 1)) * 16 + i) * 64 + lane] = acc1[i];
  }
  __syncthreads();
  if (kq == 0) {
#pragma unroll
    for (int q = 0; q < 4; ++q) {
      int oo = 32 + 8 * q + 4 * h;
      float v[4];
#pragma unroll
      for (int r = 0; r < 4; ++r) {
        int i = q * 4 + r;
        v[r] = acc1[i] + s_redf[((p2 * 3 + 0) * 16 + i) * 64 + lane] +
               s_redf[((p2 * 3 + 1) * 16 + i) * 64 + lane] +
               s_redf[((p2 * 3 + 2) * 16 + i) * 64 + lane] + bdef[oo + r];
      }
      ushort4 hh;
      hh.x = f2b(v[0]); hh.y = f2b(v[1]); hh.z = f2b(v[2]); hh.w = f2b(v[3]);
      *(ushort4*)(outH + pixb + oo) = hh;
    }
  }
}

// ---------------------------------------------------------------------------
extern "C" void kernel_launch(void* const* d_in, const int* in_sizes, int n_in,
                              void* d_out, int out_size, void* d_ws, size_t ws_size,
                              hipStream_t stream) {
  const float* xd = (const float*)d_in[0];
  const float* xl = (const float*)d_in[1];
  const float* xr = (const float*)d_in[2];
  const float* up_w = (const float*)d_in[3];
  const float* up_b = (const float*)d_in[4];
  const float* offl_w = (const float*)d_in[5];
  const float* offl_b = (const float*)d_in[6];
  const float* dl_w = (const float*)d_in[7];
  const float* dl_b = (const float*)d_in[8];
  const float* offr_w = (const float*)d_in[9];
  const float* offr_b = (const float*)d_in[10];
  const float* dr_w = (const float*)d_in[11];
  const float* dr_b = (const float*)d_in[12];
  const float* cv_w = (const float*)d_in[13];
  const float* cv_b = (const float*)d_in[14];
  const float* rb1_w1 = (const float*)d_in[15];
  const float* rb1_w2 = (const float*)d_in[16];
  const float* rb2_w1 = (const float*)d_in[17];
  const float* rb2_w2 = (const float*)d_in[18];
  const float* rb1_b1 = (const float*)d_in[19];
  const float* rb1_b2 = (const float*)d_in[20];
  const float* rb2_b1 = (const float*)d_in[21];
  const float* rb2_b2 = (const float*)d_in[22];

  float* ws = (float*)d_ws;
  u16* hb = (u16*)(ws + 1769472);
  u16* xlh = hb;                   // 2097152 each
  u16* xrh = hb + 2097152;
  u16* xdph = hb + 4194304;
  u16* xl2h = hb + 6291456;
  u16* xr2h = hb + 8388608;
  u16* t0h = hb + 10485760;
  u16* t1h = hb + 12582912;
  u16* t2h = hb + 14680064;
  u16* t3h = hb + 16777216;
  u16* xdh = hb + 18874368;        // 1048576 (2*64*64*128)
  u16* wcv = hb + 19922944;        // 110592
  u16* wofl = hb + 20033536;       // 55296
  u16* wofr = hb + 20088832;       // 55296
  u16* wr1a = hb + 20144128;       // 36864
  u16* wr1b = hb + 20180992;
  u16* wr2a = hb + 20217856;
  u16* wr2b = hb + 20254720;
  u16* wdl = hb + 20291584;        // 36864
  u16* wdr = hb + 20328448;        // 36864
  u16* wup = hb + 20365312;        // 32768
  float* outp = (float*)d_out;

  hipLaunchKernelGGL(setup_kernel, dim3(2496), dim3(256), 0, stream,
                     dl_w, dr_w, up_w, cv_w, offl_w, offr_w, rb1_w1, rb1_w2,
                     rb2_w1, rb2_w2, wup, wdl, wdr, wcv, wofl, wofr, wr1a,
                     wr1b, wr2a, wr2b, xl, xr, xlh, xrh, xd, xdh);
  hipLaunchKernelGGL(upconv_mf, dim3(128, 2), dim3(1024), 0, stream,
                     xdh, wup, up_b, xdph);
  hipLaunchKernelGGL(deform_fused, dim3(256, 2), dim3(512), 0, stream,
                     xlh, xrh, xdph, wofl, offl_b, xlh, wdl, dl_b, xl2h);
  hipLaunchKernelGGL(deform_fused, dim3(256, 2), dim3(512), 0, stream,
                     xl2h, xrh, xdph, wofr, offr_b, xrh, wdr, dr_b, xr2h);
  hipLaunchKernelGGL(mfconv_s<3>, dim3(128, 2), dim3(1024), 0, stream,
                     xl2h, xr2h, xdph, wcv, cv_b, (const u16*)nullptr,
                     (float*)nullptr, t0h, 1);
  hipLaunchKernelGGL(rbfuse, dim3(128, 2), dim3(512), 0, stream,
                     t0h, wr1a, rb1_b1, wr1b, rb1_b2, (float*)nullptr, t2h);
  hipLaunchKernelGGL(rbfuse, dim3(128, 2), dim3(512), 0, stream,
                     t2h, wr2a, rb2_b1, wr2b, rb2_b2, outp, (u16*)nullptr);
}